// Round 12
// baseline (130.073 us; speedup 1.0000x reference)
//
#include <hip/hip_runtime.h>
#include <stdint.h>

#define EMBED 384
#define NHEAD 6
#define HSZ   64
#define BATCH 32
#define SEQ   768
#define MROWS (BATCH * SEQ)   // 24576
#define NTILE (SEQ / 64)      // 12

typedef __bf16 bf16x8 __attribute__((ext_vector_type(8)));
typedef float  f32x4  __attribute__((ext_vector_type(4)));

#define GLD16(gp, lp)                                                        \
  __builtin_amdgcn_global_load_lds(                                          \
      (const __attribute__((address_space(1))) void*)(gp),                   \
      (__attribute__((address_space(3))) void*)(lp), 16, 0, 0)

__device__ inline unsigned short nbf(float f) {   // native RNE convert
  union { __bf16 b; unsigned short s; } c; c.b = (__bf16)f; return c.s;
}
__device__ inline uint32_t pk2(float a, float b) { // -> v_cvt_pk_bf16_f32
  union { __bf16 b[2]; uint32_t u; } c;
  c.b[0] = (__bf16)a; c.b[1] = (__bf16)b; return c.u;
}

// ---------------- fp32 -> bf16 convert (weights only; X converted in-GEMM) --
__global__ __launch_bounds__(256) void cvtW(const float* __restrict__ a,
                                            const float* __restrict__ b,
                                            const float* __restrict__ c,
                                            const float* __restrict__ d,
                                            unsigned short* __restrict__ dst) {
  const int NWc = EMBED * EMBED;
  int i = (blockIdx.x * 256 + threadIdx.x) * 4;
  int wsel = i / NWc, r = i - wsel * NWc;
  const float* s = ((wsel == 0) ? a : (wsel == 1) ? b : (wsel == 2) ? c : d) + r;
  float4 v = *reinterpret_cast<const float4*>(s);
  uint2 o;
  o.x = pk2(v.x, v.y); o.y = pk2(v.z, v.w);
  *reinterpret_cast<uint2*>(dst + i) = o;
}

// ---------------- GEMM: C[m,n] = sum_k A[m,k] * B[n,k]  (B stored [N][K]) ----
// 2-phase double-buffered staging; XCD-chunked bijective swizzle, n-fastest.
// MODE 0: A is fp32 X, reg-staged + converted to bf16 during staging (T14
//         issue-early/write-late); scatters Q/K bf16 (Q scaled 0.125);
//         V transposed to VT[bh][d][t].
// MODE 1: A bf16 (gload_lds staging); fp32 out + bias.
template <int MODE>
__global__ __launch_bounds__(256) void gemm_bt(
    const void* __restrict__ Ap,
    const unsigned short* __restrict__ Bw,
    unsigned short* __restrict__ Qb,
    unsigned short* __restrict__ Kb,
    unsigned short* __restrict__ VT,
    float* __restrict__ Co,
    const float* __restrict__ bias) {
  constexpr int NB = (MODE == 0) ? 9 : 3;          // n-blocks per m-panel
  constexpr int NWG = (MROWS / 128) * NB;          // 1728 / 576, both %8==0
  __shared__ __align__(16) short SH[32768];   // 64KB: 2 bufs x (A 16KB + B 16KB)
  const int tid = threadIdx.x;
  const int lane = tid & 63;
  const int w = tid >> 6;
  const int wm = w >> 1, wn = w & 1;
  // XCD-chunked bijective swizzle (m204): XCD x gets work [x*NWG/8,(x+1)*NWG/8)
  const int work = ((int)blockIdx.x % 8) * (NWG / 8) + (int)blockIdx.x / 8;
  const int m0 = (work / NB) * 128, n0 = (work % NB) * 128;
  const int l15 = lane & 15, lg = lane >> 4;
  char* shc = (char*)SH;

  // ---- staging helpers ----
  auto stageA_load = [&](int kt, float4* rg) {     // MODE 0: fp32 A -> regs
    const float* Xf = (const float*)Ap;
    const int k0 = kt * 64;
#pragma unroll
    for (int j = 0; j < 4; ++j) {
      const int u = j * 256 + tid;
      const int row = u >> 3, un = u & 7;
      const float* g = Xf + (size_t)(m0 + row) * EMBED + k0 + ((un ^ (row & 7)) * 8);
      rg[2 * j] = *(const float4*)(g);
      rg[2 * j + 1] = *(const float4*)(g + 4);
    }
  };
  auto stageA_write = [&](int buf, const float4* rg) {  // cvt + LDS write
    short* At = SH + buf * 16384;
#pragma unroll
    for (int j = 0; j < 4; ++j) {
      const int u = j * 256 + tid;
      union { uint32_t u4[4]; int4 i4; } cv;
      cv.u4[0] = pk2(rg[2 * j].x, rg[2 * j].y);
      cv.u4[1] = pk2(rg[2 * j].z, rg[2 * j].w);
      cv.u4[2] = pk2(rg[2 * j + 1].x, rg[2 * j + 1].y);
      cv.u4[3] = pk2(rg[2 * j + 1].z, rg[2 * j + 1].w);
      *(int4*)(At + u * 8) = cv.i4;
    }
  };
  auto stageAb = [&](int kt, int buf) {            // MODE 1: bf16 A gload_lds
    const unsigned short* Ab = (const unsigned short*)Ap;
    short* At = SH + buf * 16384;
    const int k0 = kt * 64;
#pragma unroll
    for (int j = 0; j < 4; ++j) {
      const int u = j * 256 + tid;
      const int row = u >> 3, un = u & 7;
      GLD16(Ab + (size_t)(m0 + row) * EMBED + k0 + ((un ^ (row & 7)) * 8),
            At + (j * 256 + (tid & ~63)) * 8);
    }
  };
  auto stageB = [&](int kt, int buf) {
    short* Bt = SH + buf * 16384 + 8192;
    const int k0 = kt * 64;
#pragma unroll
    for (int j = 0; j < 4; ++j) {
      const int u = j * 256 + tid;
      const int row = u >> 3, un = u & 7;
      GLD16(Bw + (size_t)(n0 + row) * EMBED + k0 + ((un ^ (row & 7)) * 8),
            Bt + (j * 256 + (tid & ~63)) * 8);
    }
  };

  f32x4 acc[4][4];
#pragma unroll
  for (int i = 0; i < 4; ++i)
#pragma unroll
    for (int j = 0; j < 4; ++j) acc[i][j] = f32x4{0.f, 0.f, 0.f, 0.f};

  float4 ar[8];
  if (MODE == 0) {
    stageA_load(0, ar);
    stageB(0, 0);
    stageA_write(0, ar);        // vmcnt wait auto-inserted before cvt
  } else {
    stageAb(0, 0);
    stageB(0, 0);
  }
  int cur = 0;
#pragma unroll 1
  for (int kt = 0; kt < 6; ++kt) {
    __syncthreads();                        // buf[cur] fully staged
    if (kt < 5) {                           // issue next-tile loads early
      if (MODE == 0) stageA_load(kt + 1, ar);
      else stageAb(kt + 1, cur ^ 1);
      stageB(kt + 1, cur ^ 1);
    }
    const char* Ac = shc + cur * 32768;
    const char* Bc = Ac + 16384;
#pragma unroll
    for (int kc = 0; kc < 2; ++kc) {
      bf16x8 af[4], bfr[4];
#pragma unroll
      for (int mt = 0; mt < 4; ++mt) {
        const int row = wm * 64 + mt * 16 + l15;
        af[mt] = *(const bf16x8*)(Ac + row * 128 + (((kc * 4 + lg) ^ (row & 7)) * 16));
      }
#pragma unroll
      for (int nt = 0; nt < 4; ++nt) {
        const int row = wn * 64 + nt * 16 + l15;
        bfr[nt] = *(const bf16x8*)(Bc + row * 128 + (((kc * 4 + lg) ^ (row & 7)) * 16));
      }
#pragma unroll
      for (int mt = 0; mt < 4; ++mt)
#pragma unroll
        for (int nt = 0; nt < 4; ++nt)
          acc[mt][nt] = __builtin_amdgcn_mfma_f32_16x16x32_bf16(
              af[mt], bfr[nt], acc[mt][nt], 0, 0, 0);
    }
    if (MODE == 0 && kt < 5) stageA_write(cur ^ 1, ar);  // write-late (T14)
    cur ^= 1;
  }

  if (MODE == 0 && n0 >= 768) {
    // ---- V blocks: transpose via LDS (reuse buf0, 32KB), write VT coalesced --
    const int b = m0 / SEQ, t0 = m0 - b * SEQ;
    __syncthreads();
#pragma unroll
    for (int mt = 0; mt < 4; ++mt)
#pragma unroll
      for (int nt = 0; nt < 4; ++nt)
#pragma unroll
        for (int r = 0; r < 4; ++r) {
          const int tl = wm * 64 + mt * 16 + lg * 4 + r;
          const int nl = wn * 64 + nt * 16 + l15;
          *(unsigned short*)(shc + nl * 256 + (((tl >> 3) ^ (nl & 7)) * 16) +
                             (tl & 7) * 2) = nbf(acc[mt][nt][r]);
        }
    __syncthreads();
#pragma unroll
    for (int j = 0; j < 8; ++j) {
      const int u = j * 256 + tid;
      const int row = u >> 4, un = u & 15;
      int4 vv = *(const int4*)(shc + row * 256 + ((un ^ (row & 7)) * 16));
      const int cg = (n0 - 768) + row;
      const int h = cg >> 6, d = cg & 63;
      *(int4*)(VT + ((size_t)(b * NHEAD + h) * HSZ + d) * SEQ + t0 + un * 8) = vv;
    }
    return;
  }

#pragma unroll
  for (int mt = 0; mt < 4; ++mt) {
#pragma unroll
    for (int nt = 0; nt < 4; ++nt) {
#pragma unroll
      for (int r = 0; r < 4; ++r) {
        const int m = m0 + wm * 64 + mt * 16 + lg * 4 + r;
        const int n = n0 + wn * 64 + nt * 16 + l15;
        const float v = acc[mt][nt][r];
        if (MODE == 0) {
          const int which = n / EMBED;   // 0=Q, 1=K here (V handled above)
          const int c = n - which * EMBED;
          const int h = c >> 6, d = c & 63;
          const int b = m / SEQ, t = m - b * SEQ;
          const size_t off = ((size_t)((b * NHEAD + h) * SEQ + t)) * HSZ + d;
          unsigned short* dstp = (which == 0) ? Qb : Kb;
          dstp[off] = nbf(which == 0 ? v * 0.125f : v);  // fold 1/sqrt(D) into Q
        } else {
          Co[(size_t)m * EMBED + n] = v + bias[n];
        }
      }
    }
  }
}

// ---------------- flash attention, causal, TRIPLE q-tiles per block ----------
// grid (8, 96): bh = (by/4)*8+bx (same-bh blocks share an XCD's L2).
// One staged K/V tile feeds up to 3 tile() calls; kf AND vf hoisted to regs
// once per staged tile and shared by all three.
__global__ __launch_bounds__(256, 3) void attn(const unsigned short* __restrict__ Qb,
                                               const unsigned short* __restrict__ Kb,
                                               const unsigned short* __restrict__ VT,
                                               unsigned short* __restrict__ AO) {
  __shared__ __align__(16) short Kt[2][64 * 64];   // [kv][d] swizzled, dbuf
  __shared__ __align__(16) short Vt[2][64 * 64];   // [d][kv] swizzled, dbuf
  __shared__ __align__(16) short Pl[4][16 * 64];   // per-wave P[q][kv] swizzled
  const int tid = threadIdx.x, lane = tid & 63, w = tid >> 6;
  const int l15 = lane & 15, lg = lane >> 4;
  const int trip = blockIdx.y & 3;
  const int bh = (blockIdx.y >> 2) * 8 + blockIdx.x;
  // balanced triples of q-tiles (each Σ(qt+1) = 19 or 20):
  const int q0t = trip;                                            // 0 1 2 3
  const int q1t = (trip == 3) ? 4 : trip + 5;                      // 5 6 7 4
  const int q2t = (trip == 0) ? 11 : (trip == 1) ? 10 : (trip == 2) ? 8 : 9;
  const size_t base = (size_t)bh * SEQ * HSZ;      // Qb/Kb [bh][t][d]
  char* pw = (char*)(&Pl[w][0]);

  bf16x8 qf0[2], qf1[2], qf2[2];
#pragma unroll
  for (int kc = 0; kc < 2; ++kc) {
    qf0[kc] = *(const bf16x8*)(Qb + base + (size_t)(q0t * 64 + w * 16 + l15) * HSZ +
                               kc * 32 + lg * 8);
    qf1[kc] = *(const bf16x8*)(Qb + base + (size_t)(q1t * 64 + w * 16 + l15) * HSZ +
                               kc * 32 + lg * 8);
    qf2[kc] = *(const bf16x8*)(Qb + base + (size_t)(q2t * 64 + w * 16 + l15) * HSZ +
                               kc * 32 + lg * 8);
  }

  f32x4 o0[4], o1[4], o2[4];
  float m0s = -3.0e38f, l0s = 0.f, m1s = -3.0e38f, l1s = 0.f;
  float m2s = -3.0e38f, l2s = 0.f;
#pragma unroll
  for (int nt = 0; nt < 4; ++nt) {
    o0[nt] = f32x4{0.f, 0.f, 0.f, 0.f};
    o1[nt] = f32x4{0.f, 0.f, 0.f, 0.f};
    o2[nt] = f32x4{0.f, 0.f, 0.f, 0.f};
  }

  auto stage = [&](int kt, int buf) {
#pragma unroll
    for (int j = 0; j < 2; ++j) {
      const int u = j * 256 + tid;
      const int row = u >> 3, un = u & 7;
      const int sw = (un ^ (row & 7)) * 8;
      const int ub = (j * 256 + (tid & ~63)) * 8;
      GLD16(Kb + base + (size_t)(kt * 64 + row) * HSZ + sw, &Kt[buf][ub]);
      GLD16(VT + base + (size_t)row * SEQ + kt * 64 + sw, &Vt[buf][ub]);
    }
  };

  bf16x8 kf[2][4], vf[2][4];   // hoisted once per staged tile, shared x3

  // tile: S^T = mfma(K,Q); lane owns q=l15; O^T += mfma(V^T,P)
  auto tile = [&](const bf16x8* qf, f32x4* o, float& m, float& l, bool diag) {
    f32x4 s[4];
#pragma unroll
    for (int nt = 0; nt < 4; ++nt) s[nt] = f32x4{0.f, 0.f, 0.f, 0.f};
    __builtin_amdgcn_s_setprio(1);
#pragma unroll
    for (int kc = 0; kc < 2; ++kc)
#pragma unroll
      for (int nt = 0; nt < 4; ++nt)
        s[nt] = __builtin_amdgcn_mfma_f32_16x16x32_bf16(kf[kc][nt], qf[kc], s[nt],
                                                        0, 0, 0);
    __builtin_amdgcn_s_setprio(0);
    if (diag) {
#pragma unroll
      for (int nt = 0; nt < 4; ++nt)
#pragma unroll
        for (int r = 0; r < 4; ++r)
          if (nt * 16 + lg * 4 + r > w * 16 + l15) s[nt][r] = -3.0e38f;
    }
    float mx = s[0][0];
#pragma unroll
    for (int nt = 0; nt < 4; ++nt)
#pragma unroll
      for (int r = 0; r < 4; ++r) mx = fmaxf(mx, s[nt][r]);
    mx = fmaxf(mx, __shfl_xor(mx, 16, 64));
    mx = fmaxf(mx, __shfl_xor(mx, 32, 64));
    const float mn = fmaxf(m, mx);
    const float alpha = __expf(m - mn);
    m = mn;
    float srow = 0.f;
#pragma unroll
    for (int nt = 0; nt < 4; ++nt)
#pragma unroll
      for (int r = 0; r < 4; ++r) {
        const float e = __expf(s[nt][r] - mn);
        s[nt][r] = e;
        srow += e;
      }
    srow += __shfl_xor(srow, 16, 64);
    srow += __shfl_xor(srow, 32, 64);
    l = l * alpha + srow;
#pragma unroll
    for (int nt = 0; nt < 4; ++nt) o[nt] *= alpha;
#pragma unroll
    for (int nt = 0; nt < 4; ++nt) {
      const int kv = nt * 16 + lg * 4;
      int2 pv;
      pv.x = (int)pk2(s[nt][0], s[nt][1]);
      pv.y = (int)pk2(s[nt][2], s[nt][3]);
      *(int2*)(pw + l15 * 128 + (((kv >> 3) ^ (l15 & 7)) * 16) + (kv & 7) * 2) = pv;
    }
    asm volatile("" ::: "memory");
    bf16x8 pf[2];
#pragma unroll
    for (int kc = 0; kc < 2; ++kc)
      pf[kc] = *(const bf16x8*)(pw + l15 * 128 + (((kc * 4 + lg) ^ (l15 & 7)) * 16));
    __builtin_amdgcn_s_setprio(1);
#pragma unroll
    for (int kc = 0; kc < 2; ++kc)
#pragma unroll
      for (int nt = 0; nt < 4; ++nt)
        o[nt] = __builtin_amdgcn_mfma_f32_16x16x32_bf16(vf[kc][nt], pf[kc], o[nt],
                                                        0, 0, 0);
    __builtin_amdgcn_s_setprio(0);
  };

  stage(0, 0);
  int cur = 0;
#pragma unroll 1
  for (int kt = 0; kt <= q2t; ++kt) {
    __syncthreads();                        // buf[cur] staged; buf[cur^1] free
    if (kt < q2t) stage(kt + 1, cur ^ 1);   // loads fly under compute
    const char* Kc = (const char*)Kt[cur];
    const char* Vc = (const char*)Vt[cur];
#pragma unroll
    for (int kc = 0; kc < 2; ++kc)
#pragma unroll
      for (int nt = 0; nt < 4; ++nt) {
        const int row = nt * 16 + l15;
        const int sw = ((kc * 4 + lg) ^ (row & 7)) * 16;
        kf[kc][nt] = *(const bf16x8*)(Kc + row * 128 + sw);
        vf[kc][nt] = *(const bf16x8*)(Vc + row * 128 + sw);
      }
    tile(qf2, o2, m2s, l2s, kt == q2t);
    if (kt <= q1t) tile(qf1, o1, m1s, l1s, kt == q1t);
    if (kt <= q0t) tile(qf0, o0, m0s, l0s, kt == q0t);
    cur ^= 1;
  }

  // epilogue: lane holds O[q=l15][d=nt*16+lg*4+r]; ushort4 stores x3
  const int bq = bh / NHEAD, h = bh - bq * NHEAD;
  const float inv0 = 1.f / l0s, inv1 = 1.f / l1s, inv2 = 1.f / l2s;
#pragma unroll
  for (int nt = 0; nt < 4; ++nt) {
    ushort4 s0, s1, s2;
    s0.x = nbf(o0[nt][0] * inv0); s0.y = nbf(o0[nt][1] * inv0);
    s0.z = nbf(o0[nt][2] * inv0); s0.w = nbf(o0[nt][3] * inv0);
    s1.x = nbf(o1[nt][0] * inv1); s1.y = nbf(o1[nt][1] * inv1);
    s1.z = nbf(o1[nt][2] * inv1); s1.w = nbf(o1[nt][3] * inv1);
    s2.x = nbf(o2[nt][0] * inv2); s2.y = nbf(o2[nt][1] * inv2);
    s2.z = nbf(o2[nt][2] * inv2); s2.w = nbf(o2[nt][3] * inv2);
    const int col = h * HSZ + nt * 16 + lg * 4;
    *(ushort4*)(AO + ((size_t)(bq * SEQ + q0t * 64 + w * 16 + l15)) * EMBED + col) = s0;
    *(ushort4*)(AO + ((size_t)(bq * SEQ + q1t * 64 + w * 16 + l15)) * EMBED + col) = s1;
    *(ushort4*)(AO + ((size_t)(bq * SEQ + q2t * 64 + w * 16 + l15)) * EMBED + col) = s2;
  }
}

extern "C" void kernel_launch(void* const* d_in, const int* in_sizes, int n_in,
                              void* d_out, int out_size, void* d_ws, size_t ws_size,
                              hipStream_t stream) {
  const float* X  = (const float*)d_in[0];
  const float* Wq = (const float*)d_in[1];
  const float* Wk = (const float*)d_in[2];
  const float* Wv = (const float*)d_in[3];
  const float* Wo = (const float*)d_in[4];
  const float* bo = (const float*)d_in[5];
  float* out = (float*)d_out;

  const size_t NW = (size_t)EMBED * EMBED;   // 147456
  const size_t NX = (size_t)MROWS * EMBED;   // 9437184
  unsigned short* ws    = (unsigned short*)d_ws;
  unsigned short* Wqkvb = ws;                // 3*NW
  unsigned short* Wob   = Wqkvb + 3 * NW;    // NW (contiguous after Wqkvb)
  unsigned short* AOb   = Wob + NW;          // NX  (attn output, bf16)
  unsigned short* Qb    = AOb + NX;          // NX  [B,H,T,D]
  unsigned short* Kb    = Qb + NX;           // NX  [B,H,T,D]
  unsigned short* VTb   = Kb + NX;           // NX  [B,H,D,T] (transposed V)
  // total: 4*NW + 4*NX ushorts = 76.7 MB of d_ws

  cvtW<<<(int)(4 * NW / 4 / 256), 256, 0, stream>>>(Wq, Wk, Wv, Wo, Wqkvb);

  gemm_bt<0><<<(MROWS / 128) * 9, 256, 0, stream>>>(
      X, Wqkvb, Qb, Kb, VTb, nullptr, nullptr);

  attn<<<dim3(8, 96), 256, 0, stream>>>(Qb, Kb, VTb, AOb);

  gemm_bt<1><<<(MROWS / 128) * 3, 256, 0, stream>>>(
      AOb, Wob, nullptr, nullptr, nullptr, out, bo);
}

// Round 13
// 117.357 us; speedup vs baseline: 1.1084x; 1.1084x over previous
//
#include <hip/hip_runtime.h>
#include <stdint.h>

#define EMBED 384
#define NHEAD 6
#define HSZ   64
#define BATCH 32
#define SEQ   768
#define MROWS (BATCH * SEQ)   // 24576
#define NTILE (SEQ / 64)      // 12

typedef __bf16 bf16x8 __attribute__((ext_vector_type(8)));
typedef float  f32x4  __attribute__((ext_vector_type(4)));

#define GLD16(gp, lp)                                                        \
  __builtin_amdgcn_global_load_lds(                                          \
      (const __attribute__((address_space(1))) void*)(gp),                   \
      (__attribute__((address_space(3))) void*)(lp), 16, 0, 0)

__device__ inline unsigned short nbf(float f) {   // native RNE convert
  union { __bf16 b; unsigned short s; } c; c.b = (__bf16)f; return c.s;
}
__device__ inline uint32_t pk2(float a, float b) { // -> v_cvt_pk_bf16_f32
  union { __bf16 b[2]; uint32_t u; } c;
  c.b[0] = (__bf16)a; c.b[1] = (__bf16)b; return c.u;
}

// ---------------- fused fp32 -> bf16 convert: X then Wq|Wk|Wv|Wo ------------
__global__ __launch_bounds__(256) void cvtAll(const float* __restrict__ X,
                                              const float* __restrict__ Wq,
                                              const float* __restrict__ Wk,
                                              const float* __restrict__ Wv,
                                              const float* __restrict__ Wo,
                                              unsigned short* __restrict__ dstW,
                                              unsigned short* __restrict__ dstX) {
  const int NX = MROWS * EMBED, NW = EMBED * EMBED;
  int i = (blockIdx.x * 256 + threadIdx.x) * 4;
  const float* src;
  unsigned short* dst;
  if (i < NX) {
    src = X + i; dst = dstX + i;
  } else {
    int j = i - NX;
    int wsel = j / NW, r = j - wsel * NW;
    src = ((wsel == 0) ? Wq : (wsel == 1) ? Wk : (wsel == 2) ? Wv : Wo) + r;
    dst = dstW + j;
  }
  float4 v = *reinterpret_cast<const float4*>(src);
  uint2 o;
  o.x = pk2(v.x, v.y); o.y = pk2(v.z, v.w);
  *reinterpret_cast<uint2*>(dst) = o;
}

// ---------------- GEMM: C[m,n] = sum_k A[m,k] * B[n,k]  (B stored [N][K]) ----
// R6-proven body. 1D grid, XCD-chunked bijective swizzle + n-fastest decompose.
// MODE 0: NB=9; scatters Q/K bf16 (Q scaled 0.125); V transposed VT[bh][d][t].
// MODE 1: NB=3; fp32 out + bias.
template <int MODE>
__global__ __launch_bounds__(256) void gemm_bt(
    const unsigned short* __restrict__ Ab,
    const unsigned short* __restrict__ Bw,
    unsigned short* __restrict__ Qb,
    unsigned short* __restrict__ Kb,
    unsigned short* __restrict__ VT,
    float* __restrict__ Co,
    const float* __restrict__ bias) {
  constexpr int NB = (MODE == 0) ? 9 : 3;          // n-blocks per m-panel
  constexpr int NWG = (MROWS / 128) * NB;          // 1728 / 576, both %8==0
  __shared__ __align__(16) short SH[32768];   // 64KB: 2 bufs x (A 16KB + B 16KB)
  const int tid = threadIdx.x;
  const int lane = tid & 63;
  const int w = tid >> 6;
  const int wm = w >> 1, wn = w & 1;
  // XCD-chunked bijective swizzle (m204): XCD x gets work [x*NWG/8,(x+1)*NWG/8)
  const int work = ((int)blockIdx.x % 8) * (NWG / 8) + (int)blockIdx.x / 8;
  const int m0 = (work / NB) * 128, n0 = (work % NB) * 128;
  const int l15 = lane & 15, lg = lane >> 4;
  char* shc = (char*)SH;

  auto stage = [&](int kt, int buf) {
    short* At = SH + buf * 16384;
    short* Bt = At + 8192;
    const int k0 = kt * 64;
#pragma unroll
    for (int j = 0; j < 4; ++j) {
      const int u = j * 256 + tid;
      const int row = u >> 3, un = u & 7;
      const int sw = (un ^ (row & 7)) * 8;
      const int ub = (j * 256 + (tid & ~63)) * 8;
      GLD16(Ab + (size_t)(m0 + row) * EMBED + k0 + sw, At + ub);
      GLD16(Bw + (size_t)(n0 + row) * EMBED + k0 + sw, Bt + ub);
    }
  };

  f32x4 acc[4][4];
#pragma unroll
  for (int i = 0; i < 4; ++i)
#pragma unroll
    for (int j = 0; j < 4; ++j) acc[i][j] = f32x4{0.f, 0.f, 0.f, 0.f};

  stage(0, 0);
  int cur = 0;
#pragma unroll 1
  for (int kt = 0; kt < 6; ++kt) {
    __syncthreads();                        // drains stage(kt) [vmcnt(0) auto]
    if (kt < 5) stage(kt + 1, cur ^ 1);     // next-tile loads fly under MFMA
    const char* Ac = shc + cur * 32768;
    const char* Bc = Ac + 16384;
#pragma unroll
    for (int kc = 0; kc < 2; ++kc) {
      bf16x8 af[4], bfr[4];
#pragma unroll
      for (int mt = 0; mt < 4; ++mt) {
        const int row = wm * 64 + mt * 16 + l15;
        af[mt] = *(const bf16x8*)(Ac + row * 128 + (((kc * 4 + lg) ^ (row & 7)) * 16));
      }
#pragma unroll
      for (int nt = 0; nt < 4; ++nt) {
        const int row = wn * 64 + nt * 16 + l15;
        bfr[nt] = *(const bf16x8*)(Bc + row * 128 + (((kc * 4 + lg) ^ (row & 7)) * 16));
      }
#pragma unroll
      for (int mt = 0; mt < 4; ++mt)
#pragma unroll
        for (int nt = 0; nt < 4; ++nt)
          acc[mt][nt] = __builtin_amdgcn_mfma_f32_16x16x32_bf16(
              af[mt], bfr[nt], acc[mt][nt], 0, 0, 0);
    }
    cur ^= 1;
  }

  if (MODE == 0 && n0 >= 768) {
    // ---- V blocks: transpose via LDS (reuse buf0, 32KB), write VT coalesced --
    const int b = m0 / SEQ, t0 = m0 - b * SEQ;
    __syncthreads();
#pragma unroll
    for (int mt = 0; mt < 4; ++mt)
#pragma unroll
      for (int nt = 0; nt < 4; ++nt)
#pragma unroll
        for (int r = 0; r < 4; ++r) {
          const int tl = wm * 64 + mt * 16 + lg * 4 + r;
          const int nl = wn * 64 + nt * 16 + l15;
          *(unsigned short*)(shc + nl * 256 + (((tl >> 3) ^ (nl & 7)) * 16) +
                             (tl & 7) * 2) = nbf(acc[mt][nt][r]);
        }
    __syncthreads();
#pragma unroll
    for (int j = 0; j < 8; ++j) {
      const int u = j * 256 + tid;
      const int row = u >> 4, un = u & 15;
      int4 vv = *(const int4*)(shc + row * 256 + ((un ^ (row & 7)) * 16));
      const int cg = (n0 - 768) + row;
      const int h = cg >> 6, d = cg & 63;
      *(int4*)(VT + ((size_t)(b * NHEAD + h) * HSZ + d) * SEQ + t0 + un * 8) = vv;
    }
    return;
  }

#pragma unroll
  for (int mt = 0; mt < 4; ++mt) {
#pragma unroll
    for (int nt = 0; nt < 4; ++nt) {
#pragma unroll
      for (int r = 0; r < 4; ++r) {
        const int m = m0 + wm * 64 + mt * 16 + lg * 4 + r;
        const int n = n0 + wn * 64 + nt * 16 + l15;
        const float v = acc[mt][nt][r];
        if (MODE == 0) {
          const int which = n / EMBED;   // 0=Q, 1=K here (V handled above)
          const int c = n - which * EMBED;
          const int h = c >> 6, d = c & 63;
          const int b = m / SEQ, t = m - b * SEQ;
          const size_t off = ((size_t)((b * NHEAD + h) * SEQ + t)) * HSZ + d;
          unsigned short* dstp = (which == 0) ? Qb : Kb;
          dstp[off] = nbf(which == 0 ? v * 0.125f : v);  // fold 1/sqrt(D) into Q
        } else {
          Co[(size_t)m * EMBED + n] = v + bias[n];
        }
      }
    }
  }
}

// ---------------- flash attention, causal, TRIPLE q-tiles per block ----------
// grid (8, 96): bh = (by/4)*8+bx (same-bh blocks share an XCD's L2).
// One staged K/V tile feeds up to 3 tile() calls; kf AND vf hoisted to regs
// once per staged tile and shared by all three (single delta vs R11).
__global__ __launch_bounds__(256, 3) void attn(const unsigned short* __restrict__ Qb,
                                               const unsigned short* __restrict__ Kb,
                                               const unsigned short* __restrict__ VT,
                                               unsigned short* __restrict__ AO) {
  __shared__ __align__(16) short Kt[2][64 * 64];   // [kv][d] swizzled, dbuf
  __shared__ __align__(16) short Vt[2][64 * 64];   // [d][kv] swizzled, dbuf
  __shared__ __align__(16) short Pl[4][16 * 64];   // per-wave P[q][kv] swizzled
  const int tid = threadIdx.x, lane = tid & 63, w = tid >> 6;
  const int l15 = lane & 15, lg = lane >> 4;
  const int trip = blockIdx.y & 3;
  const int bh = (blockIdx.y >> 2) * 8 + blockIdx.x;
  // balanced triples of q-tiles (each Σ(qt+1) = 19 or 20):
  const int q0t = trip;                                            // 0 1 2 3
  const int q1t = (trip == 3) ? 4 : trip + 5;                      // 5 6 7 4
  const int q2t = (trip == 0) ? 11 : (trip == 1) ? 10 : (trip == 2) ? 8 : 9;
  const size_t base = (size_t)bh * SEQ * HSZ;      // Qb/Kb [bh][t][d]
  char* pw = (char*)(&Pl[w][0]);

  bf16x8 qf0[2], qf1[2], qf2[2];
#pragma unroll
  for (int kc = 0; kc < 2; ++kc) {
    qf0[kc] = *(const bf16x8*)(Qb + base + (size_t)(q0t * 64 + w * 16 + l15) * HSZ +
                               kc * 32 + lg * 8);
    qf1[kc] = *(const bf16x8*)(Qb + base + (size_t)(q1t * 64 + w * 16 + l15) * HSZ +
                               kc * 32 + lg * 8);
    qf2[kc] = *(const bf16x8*)(Qb + base + (size_t)(q2t * 64 + w * 16 + l15) * HSZ +
                               kc * 32 + lg * 8);
  }

  f32x4 o0[4], o1[4], o2[4];
  float m0s = -3.0e38f, l0s = 0.f, m1s = -3.0e38f, l1s = 0.f;
  float m2s = -3.0e38f, l2s = 0.f;
#pragma unroll
  for (int nt = 0; nt < 4; ++nt) {
    o0[nt] = f32x4{0.f, 0.f, 0.f, 0.f};
    o1[nt] = f32x4{0.f, 0.f, 0.f, 0.f};
    o2[nt] = f32x4{0.f, 0.f, 0.f, 0.f};
  }

  auto stage = [&](int kt, int buf) {
#pragma unroll
    for (int j = 0; j < 2; ++j) {
      const int u = j * 256 + tid;
      const int row = u >> 3, un = u & 7;
      const int sw = (un ^ (row & 7)) * 8;
      const int ub = (j * 256 + (tid & ~63)) * 8;
      GLD16(Kb + base + (size_t)(kt * 64 + row) * HSZ + sw, &Kt[buf][ub]);
      GLD16(VT + base + (size_t)row * SEQ + kt * 64 + sw, &Vt[buf][ub]);
    }
  };

  bf16x8 kf[2][4], vf[2][4];   // hoisted once per staged tile, shared x3

  // tile: S^T = mfma(K,Q); lane owns q=l15; O^T += mfma(V^T,P)
  auto tile = [&](const bf16x8* qf, f32x4* o, float& m, float& l, bool diag) {
    f32x4 s[4];
#pragma unroll
    for (int nt = 0; nt < 4; ++nt) s[nt] = f32x4{0.f, 0.f, 0.f, 0.f};
    __builtin_amdgcn_s_setprio(1);
#pragma unroll
    for (int kc = 0; kc < 2; ++kc)
#pragma unroll
      for (int nt = 0; nt < 4; ++nt)
        s[nt] = __builtin_amdgcn_mfma_f32_16x16x32_bf16(kf[kc][nt], qf[kc], s[nt],
                                                        0, 0, 0);
    __builtin_amdgcn_s_setprio(0);
    if (diag) {
#pragma unroll
      for (int nt = 0; nt < 4; ++nt)
#pragma unroll
        for (int r = 0; r < 4; ++r)
          if (nt * 16 + lg * 4 + r > w * 16 + l15) s[nt][r] = -3.0e38f;
    }
    float mx = s[0][0];
#pragma unroll
    for (int nt = 0; nt < 4; ++nt)
#pragma unroll
      for (int r = 0; r < 4; ++r) mx = fmaxf(mx, s[nt][r]);
    mx = fmaxf(mx, __shfl_xor(mx, 16, 64));
    mx = fmaxf(mx, __shfl_xor(mx, 32, 64));
    const float mn = fmaxf(m, mx);
    const float alpha = __expf(m - mn);
    m = mn;
    float srow = 0.f;
#pragma unroll
    for (int nt = 0; nt < 4; ++nt)
#pragma unroll
      for (int r = 0; r < 4; ++r) {
        const float e = __expf(s[nt][r] - mn);
        s[nt][r] = e;
        srow += e;
      }
    srow += __shfl_xor(srow, 16, 64);
    srow += __shfl_xor(srow, 32, 64);
    l = l * alpha + srow;
#pragma unroll
    for (int nt = 0; nt < 4; ++nt) o[nt] *= alpha;
#pragma unroll
    for (int nt = 0; nt < 4; ++nt) {
      const int kv = nt * 16 + lg * 4;
      int2 pv;
      pv.x = (int)pk2(s[nt][0], s[nt][1]);
      pv.y = (int)pk2(s[nt][2], s[nt][3]);
      *(int2*)(pw + l15 * 128 + (((kv >> 3) ^ (l15 & 7)) * 16) + (kv & 7) * 2) = pv;
    }
    asm volatile("" ::: "memory");
    bf16x8 pf[2];
#pragma unroll
    for (int kc = 0; kc < 2; ++kc)
      pf[kc] = *(const bf16x8*)(pw + l15 * 128 + (((kc * 4 + lg) ^ (l15 & 7)) * 16));
    __builtin_amdgcn_s_setprio(1);
#pragma unroll
    for (int kc = 0; kc < 2; ++kc)
#pragma unroll
      for (int nt = 0; nt < 4; ++nt)
        o[nt] = __builtin_amdgcn_mfma_f32_16x16x32_bf16(vf[kc][nt], pf[kc], o[nt],
                                                        0, 0, 0);
    __builtin_amdgcn_s_setprio(0);
  };

  stage(0, 0);
  int cur = 0;
#pragma unroll 1
  for (int kt = 0; kt <= q2t; ++kt) {
    __syncthreads();                        // buf[cur] staged; buf[cur^1] free
    if (kt < q2t) stage(kt + 1, cur ^ 1);   // loads fly under compute
    const char* Kc = (const char*)Kt[cur];
    const char* Vc = (const char*)Vt[cur];
#pragma unroll
    for (int kc = 0; kc < 2; ++kc)
#pragma unroll
      for (int nt = 0; nt < 4; ++nt) {
        const int row = nt * 16 + l15;
        const int sw = ((kc * 4 + lg) ^ (row & 7)) * 16;
        kf[kc][nt] = *(const bf16x8*)(Kc + row * 128 + sw);
        vf[kc][nt] = *(const bf16x8*)(Vc + row * 128 + sw);
      }
    tile(qf2, o2, m2s, l2s, kt == q2t);
    if (kt <= q1t) tile(qf1, o1, m1s, l1s, kt == q1t);
    if (kt <= q0t) tile(qf0, o0, m0s, l0s, kt == q0t);
    cur ^= 1;
  }

  // epilogue: lane holds O[q=l15][d=nt*16+lg*4+r]; ushort4 stores x3
  const int bq = bh / NHEAD, h = bh - bq * NHEAD;
  const float inv0 = 1.f / l0s, inv1 = 1.f / l1s, inv2 = 1.f / l2s;
#pragma unroll
  for (int nt = 0; nt < 4; ++nt) {
    ushort4 s0, s1, s2;
    s0.x = nbf(o0[nt][0] * inv0); s0.y = nbf(o0[nt][1] * inv0);
    s0.z = nbf(o0[nt][2] * inv0); s0.w = nbf(o0[nt][3] * inv0);
    s1.x = nbf(o1[nt][0] * inv1); s1.y = nbf(o1[nt][1] * inv1);
    s1.z = nbf(o1[nt][2] * inv1); s1.w = nbf(o1[nt][3] * inv1);
    s2.x = nbf(o2[nt][0] * inv2); s2.y = nbf(o2[nt][1] * inv2);
    s2.z = nbf(o2[nt][2] * inv2); s2.w = nbf(o2[nt][3] * inv2);
    const int col = h * HSZ + nt * 16 + lg * 4;
    *(ushort4*)(AO + ((size_t)(bq * SEQ + q0t * 64 + w * 16 + l15)) * EMBED + col) = s0;
    *(ushort4*)(AO + ((size_t)(bq * SEQ + q1t * 64 + w * 16 + l15)) * EMBED + col) = s1;
    *(ushort4*)(AO + ((size_t)(bq * SEQ + q2t * 64 + w * 16 + l15)) * EMBED + col) = s2;
  }
}

extern "C" void kernel_launch(void* const* d_in, const int* in_sizes, int n_in,
                              void* d_out, int out_size, void* d_ws, size_t ws_size,
                              hipStream_t stream) {
  const float* X  = (const float*)d_in[0];
  const float* Wq = (const float*)d_in[1];
  const float* Wk = (const float*)d_in[2];
  const float* Wv = (const float*)d_in[3];
  const float* Wo = (const float*)d_in[4];
  const float* bo = (const float*)d_in[5];
  float* out = (float*)d_out;

  const size_t NW = (size_t)EMBED * EMBED;   // 147456
  const size_t NX = (size_t)MROWS * EMBED;   // 9437184
  unsigned short* ws    = (unsigned short*)d_ws;
  unsigned short* Wqkvb = ws;                // 3*NW
  unsigned short* Wob   = Wqkvb + 3 * NW;    // NW (contiguous after Wqkvb)
  unsigned short* XbAO  = Wob + NW;          // NX: Xb (pre-attn) then AO
  unsigned short* Qb    = XbAO + NX;         // NX  [B,H,T,D]
  unsigned short* Kb    = Qb + NX;           // NX  [B,H,T,D]
  unsigned short* VTb   = Kb + NX;           // NX  [B,H,D,T] (transposed V)
  // total: 4*NW + 4*NX ushorts = 76.7 MB of d_ws

  cvtAll<<<(int)((NX + 4 * NW) / 4 / 256), 256, 0, stream>>>(
      X, Wq, Wk, Wv, Wo, Wqkvb, XbAO);

  gemm_bt<0><<<(MROWS / 128) * 9, 256, 0, stream>>>(
      XbAO, Wqkvb, Qb, Kb, VTb, nullptr, nullptr);

  attn<<<dim3(8, 96), 256, 0, stream>>>(Qb, Kb, VTb, XbAO);

  gemm_bt<1><<<(MROWS / 128) * 3, 256, 0, stream>>>(
      XbAO, Wob, nullptr, nullptr, nullptr, out, bo);
}

// Round 14
// 107.390 us; speedup vs baseline: 1.2112x; 1.0928x over previous
//
#include <hip/hip_runtime.h>
#include <stdint.h>

#define EMBED 384
#define NHEAD 6
#define HSZ   64
#define BATCH 32
#define SEQ   768
#define MROWS (BATCH * SEQ)   // 24576
#define NTILE (SEQ / 64)      // 12

typedef __bf16 bf16x8 __attribute__((ext_vector_type(8)));
typedef float  f32x4  __attribute__((ext_vector_type(4)));

#define GLD16(gp, lp)                                                        \
  __builtin_amdgcn_global_load_lds(                                          \
      (const __attribute__((address_space(1))) void*)(gp),                   \
      (__attribute__((address_space(3))) void*)(lp), 16, 0, 0)

#define QSCALE 0.18033688011112042f   /* 0.125 * log2(e): exp2-domain scores */

__device__ inline unsigned short nbf(float f) {   // native RNE convert
  union { __bf16 b; unsigned short s; } c; c.b = (__bf16)f; return c.s;
}
__device__ inline uint32_t pk2(float a, float b) { // -> v_cvt_pk_bf16_f32
  union { __bf16 b[2]; uint32_t u; } c;
  c.b[0] = (__bf16)a; c.b[1] = (__bf16)b; return c.u;
}

// ---------------- fused fp32 -> bf16 convert: X then Wq|Wk|Wv|Wo ------------
__global__ __launch_bounds__(256) void cvtAll(const float* __restrict__ X,
                                              const float* __restrict__ Wq,
                                              const float* __restrict__ Wk,
                                              const float* __restrict__ Wv,
                                              const float* __restrict__ Wo,
                                              unsigned short* __restrict__ dstW,
                                              unsigned short* __restrict__ dstX) {
  const int NX = MROWS * EMBED, NW = EMBED * EMBED;
  int i = (blockIdx.x * 256 + threadIdx.x) * 4;
  const float* src;
  unsigned short* dst;
  if (i < NX) {
    src = X + i; dst = dstX + i;
  } else {
    int j = i - NX;
    int wsel = j / NW, r = j - wsel * NW;
    src = ((wsel == 0) ? Wq : (wsel == 1) ? Wk : (wsel == 2) ? Wv : Wo) + r;
    dst = dstW + j;
  }
  float4 v = *reinterpret_cast<const float4*>(src);
  uint2 o;
  o.x = pk2(v.x, v.y); o.y = pk2(v.z, v.w);
  *reinterpret_cast<uint2*>(dst) = o;
}

// ---------------- GEMM: C[m,n] = sum_k A[m,k] * B[n,k]  (B stored [N][K]) ----
// R6-proven body. 1D grid, XCD-chunked bijective swizzle + n-fastest decompose.
// MODE 0: NB=9; scatters Q/K bf16 (Q scaled by QSCALE); V transposed VT[bh][d][t].
// MODE 1: NB=3; fp32 out + bias.
template <int MODE>
__global__ __launch_bounds__(256) void gemm_bt(
    const unsigned short* __restrict__ Ab,
    const unsigned short* __restrict__ Bw,
    unsigned short* __restrict__ Qb,
    unsigned short* __restrict__ Kb,
    unsigned short* __restrict__ VT,
    float* __restrict__ Co,
    const float* __restrict__ bias) {
  constexpr int NB = (MODE == 0) ? 9 : 3;          // n-blocks per m-panel
  constexpr int NWG = (MROWS / 128) * NB;          // 1728 / 576, both %8==0
  __shared__ __align__(16) short SH[32768];   // 64KB: 2 bufs x (A 16KB + B 16KB)
  const int tid = threadIdx.x;
  const int lane = tid & 63;
  const int w = tid >> 6;
  const int wm = w >> 1, wn = w & 1;
  // XCD-chunked bijective swizzle (m204): XCD x gets work [x*NWG/8,(x+1)*NWG/8)
  const int work = ((int)blockIdx.x % 8) * (NWG / 8) + (int)blockIdx.x / 8;
  const int m0 = (work / NB) * 128, n0 = (work % NB) * 128;
  const int l15 = lane & 15, lg = lane >> 4;
  char* shc = (char*)SH;

  auto stage = [&](int kt, int buf) {
    short* At = SH + buf * 16384;
    short* Bt = At + 8192;
    const int k0 = kt * 64;
#pragma unroll
    for (int j = 0; j < 4; ++j) {
      const int u = j * 256 + tid;
      const int row = u >> 3, un = u & 7;
      const int sw = (un ^ (row & 7)) * 8;
      const int ub = (j * 256 + (tid & ~63)) * 8;
      GLD16(Ab + (size_t)(m0 + row) * EMBED + k0 + sw, At + ub);
      GLD16(Bw + (size_t)(n0 + row) * EMBED + k0 + sw, Bt + ub);
    }
  };

  f32x4 acc[4][4];
#pragma unroll
  for (int i = 0; i < 4; ++i)
#pragma unroll
    for (int j = 0; j < 4; ++j) acc[i][j] = f32x4{0.f, 0.f, 0.f, 0.f};

  stage(0, 0);
  int cur = 0;
#pragma unroll 1
  for (int kt = 0; kt < 6; ++kt) {
    __syncthreads();                        // drains stage(kt) [vmcnt(0) auto]
    if (kt < 5) stage(kt + 1, cur ^ 1);     // next-tile loads fly under MFMA
    const char* Ac = shc + cur * 32768;
    const char* Bc = Ac + 16384;
#pragma unroll
    for (int kc = 0; kc < 2; ++kc) {
      bf16x8 af[4], bfr[4];
#pragma unroll
      for (int mt = 0; mt < 4; ++mt) {
        const int row = wm * 64 + mt * 16 + l15;
        af[mt] = *(const bf16x8*)(Ac + row * 128 + (((kc * 4 + lg) ^ (row & 7)) * 16));
      }
#pragma unroll
      for (int nt = 0; nt < 4; ++nt) {
        const int row = wn * 64 + nt * 16 + l15;
        bfr[nt] = *(const bf16x8*)(Bc + row * 128 + (((kc * 4 + lg) ^ (row & 7)) * 16));
      }
#pragma unroll
      for (int mt = 0; mt < 4; ++mt)
#pragma unroll
        for (int nt = 0; nt < 4; ++nt)
          acc[mt][nt] = __builtin_amdgcn_mfma_f32_16x16x32_bf16(
              af[mt], bfr[nt], acc[mt][nt], 0, 0, 0);
    }
    cur ^= 1;
  }

  if (MODE == 0 && n0 >= 768) {
    // ---- V blocks: transpose via LDS (reuse buf0, 32KB), write VT coalesced --
    const int b = m0 / SEQ, t0 = m0 - b * SEQ;
    __syncthreads();
#pragma unroll
    for (int mt = 0; mt < 4; ++mt)
#pragma unroll
      for (int nt = 0; nt < 4; ++nt)
#pragma unroll
        for (int r = 0; r < 4; ++r) {
          const int tl = wm * 64 + mt * 16 + lg * 4 + r;
          const int nl = wn * 64 + nt * 16 + l15;
          *(unsigned short*)(shc + nl * 256 + (((tl >> 3) ^ (nl & 7)) * 16) +
                             (tl & 7) * 2) = nbf(acc[mt][nt][r]);
        }
    __syncthreads();
#pragma unroll
    for (int j = 0; j < 8; ++j) {
      const int u = j * 256 + tid;
      const int row = u >> 4, un = u & 15;
      int4 vv = *(const int4*)(shc + row * 256 + ((un ^ (row & 7)) * 16));
      const int cg = (n0 - 768) + row;
      const int h = cg >> 6, d = cg & 63;
      *(int4*)(VT + ((size_t)(b * NHEAD + h) * HSZ + d) * SEQ + t0 + un * 8) = vv;
    }
    return;
  }

#pragma unroll
  for (int mt = 0; mt < 4; ++mt) {
#pragma unroll
    for (int nt = 0; nt < 4; ++nt) {
#pragma unroll
      for (int r = 0; r < 4; ++r) {
        const int m = m0 + wm * 64 + mt * 16 + lg * 4 + r;
        const int n = n0 + wn * 64 + nt * 16 + l15;
        const float v = acc[mt][nt][r];
        if (MODE == 0) {
          const int which = n / EMBED;   // 0=Q, 1=K here (V handled above)
          const int c = n - which * EMBED;
          const int h = c >> 6, d = c & 63;
          const int b = m / SEQ, t = m - b * SEQ;
          const size_t off = ((size_t)((b * NHEAD + h) * SEQ + t)) * HSZ + d;
          unsigned short* dstp = (which == 0) ? Qb : Kb;
          dstp[off] = nbf(which == 0 ? v * QSCALE : v);  // exp2-domain Q scale
        } else {
          Co[(size_t)m * EMBED + n] = v + bias[n];
        }
      }
    }
  }
}

// ---------------- flash attention, causal, TRIPLE q-tiles per block ----------
// grid (8, 96): bh = (by/4)*8+bx (same-bh blocks share an XCD's L2).
// R10 structure + exp2-domain softmax, deferred l-reduction, parallel fmax tree.
// kf/vf NOT hoisted across tiles (R13: spills to scratch).
__global__ __launch_bounds__(256, 3) void attn(const unsigned short* __restrict__ Qb,
                                               const unsigned short* __restrict__ Kb,
                                               const unsigned short* __restrict__ VT,
                                               unsigned short* __restrict__ AO) {
  __shared__ __align__(16) short Kt[2][64 * 64];   // [kv][d] swizzled, dbuf
  __shared__ __align__(16) short Vt[2][64 * 64];   // [d][kv] swizzled, dbuf
  __shared__ __align__(16) short Pl[4][16 * 64];   // per-wave P[q][kv] swizzled
  const int tid = threadIdx.x, lane = tid & 63, w = tid >> 6;
  const int l15 = lane & 15, lg = lane >> 4;
  const int trip = blockIdx.y & 3;
  const int bh = (blockIdx.y >> 2) * 8 + blockIdx.x;
  // balanced triples of q-tiles (each Σ(qt+1) = 19 or 20):
  const int q0t = trip;                                            // 0 1 2 3
  const int q1t = (trip == 3) ? 4 : trip + 5;                      // 5 6 7 4
  const int q2t = (trip == 0) ? 11 : (trip == 1) ? 10 : (trip == 2) ? 8 : 9;
  const size_t base = (size_t)bh * SEQ * HSZ;      // Qb/Kb [bh][t][d]
  char* pw = (char*)(&Pl[w][0]);

  bf16x8 qf0[2], qf1[2], qf2[2];
#pragma unroll
  for (int kc = 0; kc < 2; ++kc) {
    qf0[kc] = *(const bf16x8*)(Qb + base + (size_t)(q0t * 64 + w * 16 + l15) * HSZ +
                               kc * 32 + lg * 8);
    qf1[kc] = *(const bf16x8*)(Qb + base + (size_t)(q1t * 64 + w * 16 + l15) * HSZ +
                               kc * 32 + lg * 8);
    qf2[kc] = *(const bf16x8*)(Qb + base + (size_t)(q2t * 64 + w * 16 + l15) * HSZ +
                               kc * 32 + lg * 8);
  }

  f32x4 o0[4], o1[4], o2[4];
  float m0s = -3.0e38f, l0s = 0.f, m1s = -3.0e38f, l1s = 0.f;
  float m2s = -3.0e38f, l2s = 0.f;   // l = per-lane partial (reduced in epilogue)
#pragma unroll
  for (int nt = 0; nt < 4; ++nt) {
    o0[nt] = f32x4{0.f, 0.f, 0.f, 0.f};
    o1[nt] = f32x4{0.f, 0.f, 0.f, 0.f};
    o2[nt] = f32x4{0.f, 0.f, 0.f, 0.f};
  }

  auto stage = [&](int kt, int buf) {
#pragma unroll
    for (int j = 0; j < 2; ++j) {
      const int u = j * 256 + tid;
      const int row = u >> 3, un = u & 7;
      const int sw = (un ^ (row & 7)) * 8;
      const int ub = (j * 256 + (tid & ~63)) * 8;
      GLD16(Kb + base + (size_t)(kt * 64 + row) * HSZ + sw, &Kt[buf][ub]);
      GLD16(VT + base + (size_t)row * SEQ + kt * 64 + sw, &Vt[buf][ub]);
    }
  };

  // tile: S^T = mfma(K,Q); lane owns q=l15; exp2-domain softmax; O^T += mfma(V^T,P)
  auto tile = [&](const bf16x8* qf, const bf16x8 kf[2][4], const char* Vc,
                  f32x4* o, float& m, float& lp, bool diag) {
    f32x4 s[4];
#pragma unroll
    for (int nt = 0; nt < 4; ++nt) s[nt] = f32x4{0.f, 0.f, 0.f, 0.f};
    __builtin_amdgcn_s_setprio(1);
#pragma unroll
    for (int kc = 0; kc < 2; ++kc)
#pragma unroll
      for (int nt = 0; nt < 4; ++nt)
        s[nt] = __builtin_amdgcn_mfma_f32_16x16x32_bf16(kf[kc][nt], qf[kc], s[nt],
                                                        0, 0, 0);
    __builtin_amdgcn_s_setprio(0);
    if (diag) {
#pragma unroll
      for (int nt = 0; nt < 4; ++nt)
#pragma unroll
        for (int r = 0; r < 4; ++r)
          if (nt * 16 + lg * 4 + r > w * 16 + l15) s[nt][r] = -3.0e38f;
    }
    // 4-way parallel fmax tree (was a 15-deep serial chain)
    float t0 = fmaxf(fmaxf(s[0][0], s[0][1]), fmaxf(s[0][2], s[0][3]));
    float t1 = fmaxf(fmaxf(s[1][0], s[1][1]), fmaxf(s[1][2], s[1][3]));
    float t2 = fmaxf(fmaxf(s[2][0], s[2][1]), fmaxf(s[2][2], s[2][3]));
    float t3 = fmaxf(fmaxf(s[3][0], s[3][1]), fmaxf(s[3][2], s[3][3]));
    float mx = fmaxf(fmaxf(t0, t1), fmaxf(t2, t3));
    mx = fmaxf(mx, __shfl_xor(mx, 16, 64));
    mx = fmaxf(mx, __shfl_xor(mx, 32, 64));
    const float mn = fmaxf(m, mx);
    const float alpha = __builtin_amdgcn_exp2f(m - mn);   // raw v_exp (2^x)
    m = mn;
    float srow = 0.f;
#pragma unroll
    for (int nt = 0; nt < 4; ++nt)
#pragma unroll
      for (int r = 0; r < 4; ++r) {
        const float e = __builtin_amdgcn_exp2f(s[nt][r] - mn);
        s[nt][r] = e;
        srow += e;
      }
    lp = lp * alpha + srow;   // per-lane partial; cross-lane sum in epilogue
#pragma unroll
    for (int nt = 0; nt < 4; ++nt) o[nt] *= alpha;
#pragma unroll
    for (int nt = 0; nt < 4; ++nt) {
      const int kv = nt * 16 + lg * 4;
      int2 pv;
      pv.x = (int)pk2(s[nt][0], s[nt][1]);
      pv.y = (int)pk2(s[nt][2], s[nt][3]);
      *(int2*)(pw + l15 * 128 + (((kv >> 3) ^ (l15 & 7)) * 16) + (kv & 7) * 2) = pv;
    }
    asm volatile("" ::: "memory");
    bf16x8 pf[2];
#pragma unroll
    for (int kc = 0; kc < 2; ++kc)
      pf[kc] = *(const bf16x8*)(pw + l15 * 128 + (((kc * 4 + lg) ^ (l15 & 7)) * 16));
    __builtin_amdgcn_s_setprio(1);
#pragma unroll
    for (int kc = 0; kc < 2; ++kc)
#pragma unroll
      for (int nt = 0; nt < 4; ++nt) {
        const int row = nt * 16 + l15;
        bf16x8 vf = *(const bf16x8*)(Vc + row * 128 +
                                     (((kc * 4 + lg) ^ (row & 7)) * 16));
        o[nt] = __builtin_amdgcn_mfma_f32_16x16x32_bf16(vf, pf[kc], o[nt], 0, 0, 0);
      }
    __builtin_amdgcn_s_setprio(0);
  };

  stage(0, 0);
  int cur = 0;
#pragma unroll 1
  for (int kt = 0; kt <= q2t; ++kt) {
    __syncthreads();                        // buf[cur] staged; buf[cur^1] free
    if (kt < q2t) stage(kt + 1, cur ^ 1);   // loads fly under compute
    const char* Kc = (const char*)Kt[cur];
    const char* Vc = (const char*)Vt[cur];
    bf16x8 kf[2][4];
#pragma unroll
    for (int kc = 0; kc < 2; ++kc)
#pragma unroll
      for (int nt = 0; nt < 4; ++nt) {
        const int row = nt * 16 + l15;
        kf[kc][nt] = *(const bf16x8*)(Kc + row * 128 +
                                      (((kc * 4 + lg) ^ (row & 7)) * 16));
      }
    tile(qf2, kf, Vc, o2, m2s, l2s, kt == q2t);
    if (kt <= q1t) tile(qf1, kf, Vc, o1, m1s, l1s, kt == q1t);
    if (kt <= q0t) tile(qf0, kf, Vc, o0, m0s, l0s, kt == q0t);
    cur ^= 1;
  }

  // epilogue: finish deferred l-reductions; lane holds O[q=l15][d=nt*16+lg*4+r]
  float lt0 = l0s, lt1 = l1s, lt2 = l2s;
  lt0 += __shfl_xor(lt0, 16, 64); lt0 += __shfl_xor(lt0, 32, 64);
  lt1 += __shfl_xor(lt1, 16, 64); lt1 += __shfl_xor(lt1, 32, 64);
  lt2 += __shfl_xor(lt2, 16, 64); lt2 += __shfl_xor(lt2, 32, 64);
  const int bq = bh / NHEAD, h = bh - bq * NHEAD;
  const float inv0 = 1.f / lt0, inv1 = 1.f / lt1, inv2 = 1.f / lt2;
#pragma unroll
  for (int nt = 0; nt < 4; ++nt) {
    ushort4 s0, s1, s2;
    s0.x = nbf(o0[nt][0] * inv0); s0.y = nbf(o0[nt][1] * inv0);
    s0.z = nbf(o0[nt][2] * inv0); s0.w = nbf(o0[nt][3] * inv0);
    s1.x = nbf(o1[nt][0] * inv1); s1.y = nbf(o1[nt][1] * inv1);
    s1.z = nbf(o1[nt][2] * inv1); s1.w = nbf(o1[nt][3] * inv1);
    s2.x = nbf(o2[nt][0] * inv2); s2.y = nbf(o2[nt][1] * inv2);
    s2.z = nbf(o2[nt][2] * inv2); s2.w = nbf(o2[nt][3] * inv2);
    const int col = h * HSZ + nt * 16 + lg * 4;
    *(ushort4*)(AO + ((size_t)(bq * SEQ + q0t * 64 + w * 16 + l15)) * EMBED + col) = s0;
    *(ushort4*)(AO + ((size_t)(bq * SEQ + q1t * 64 + w * 16 + l15)) * EMBED + col) = s1;
    *(ushort4*)(AO + ((size_t)(bq * SEQ + q2t * 64 + w * 16 + l15)) * EMBED + col) = s2;
  }
}

extern "C" void kernel_launch(void* const* d_in, const int* in_sizes, int n_in,
                              void* d_out, int out_size, void* d_ws, size_t ws_size,
                              hipStream_t stream) {
  const float* X  = (const float*)d_in[0];
  const float* Wq = (const float*)d_in[1];
  const float* Wk = (const float*)d_in[2];
  const float* Wv = (const float*)d_in[3];
  const float* Wo = (const float*)d_in[4];
  const float* bo = (const float*)d_in[5];
  float* out = (float*)d_out;

  const size_t NW = (size_t)EMBED * EMBED;   // 147456
  const size_t NX = (size_t)MROWS * EMBED;   // 9437184
  unsigned short* ws    = (unsigned short*)d_ws;
  unsigned short* Wqkvb = ws;                // 3*NW
  unsigned short* Wob   = Wqkvb + 3 * NW;    // NW (contiguous after Wqkvb)
  unsigned short* XbAO  = Wob + NW;          // NX: Xb (pre-attn) then AO
  unsigned short* Qb    = XbAO + NX;         // NX  [B,H,T,D]
  unsigned short* Kb    = Qb + NX;           // NX  [B,H,T,D]
  unsigned short* VTb   = Kb + NX;           // NX  [B,H,D,T] (transposed V)
  // total: 4*NW + 4*NX ushorts = 76.7 MB of d_ws

  cvtAll<<<(int)((NX + 4 * NW) / 4 / 256), 256, 0, stream>>>(
      X, Wq, Wk, Wv, Wo, Wqkvb, XbAO);

  gemm_bt<0><<<(MROWS / 128) * 9, 256, 0, stream>>>(
      XbAO, Wqkvb, Qb, Kb, VTb, nullptr, nullptr);

  attn<<<dim3(8, 96), 256, 0, stream>>>(Qb, Kb, VTb, XbAO);

  gemm_bt<1><<<(MROWS / 128) * 3, 256, 0, stream>>>(
      XbAO, Wob, nullptr, nullptr, nullptr, out, bo);
}

// Round 15
// 103.957 us; speedup vs baseline: 1.2512x; 1.0330x over previous
//
#include <hip/hip_runtime.h>
#include <stdint.h>

#define EMBED 384
#define NHEAD 6
#define HSZ   64
#define BATCH 32
#define SEQ   768
#define MROWS (BATCH * SEQ)   // 24576
#define NTILE (SEQ / 64)      // 12

typedef __bf16 bf16x8 __attribute__((ext_vector_type(8)));
typedef float  f32x4  __attribute__((ext_vector_type(4)));

#define GLD16(gp, lp)                                                        \
  __builtin_amdgcn_global_load_lds(                                          \
      (const __attribute__((address_space(1))) void*)(gp),                   \
      (__attribute__((address_space(3))) void*)(lp), 16, 0, 0)

__device__ inline unsigned short nbf(float f) {   // native RNE convert
  union { __bf16 b; unsigned short s; } c; c.b = (__bf16)f; return c.s;
}
__device__ inline uint32_t pk2(float a, float b) { // -> v_cvt_pk_bf16_f32
  union { __bf16 b[2]; uint32_t u; } c;
  c.b[0] = (__bf16)a; c.b[1] = (__bf16)b; return c.u;
}

// ---------------- fused fp32 -> bf16 convert: X then Wq|Wk|Wv|Wo ------------
__global__ __launch_bounds__(256) void cvtAll(const float* __restrict__ X,
                                              const float* __restrict__ Wq,
                                              const float* __restrict__ Wk,
                                              const float* __restrict__ Wv,
                                              const float* __restrict__ Wo,
                                              unsigned short* __restrict__ dstW,
                                              unsigned short* __restrict__ dstX) {
  const int NX = MROWS * EMBED, NW = EMBED * EMBED;
  int i = (blockIdx.x * 256 + threadIdx.x) * 4;
  const float* src;
  unsigned short* dst;
  if (i < NX) {
    src = X + i; dst = dstX + i;
  } else {
    int j = i - NX;
    int wsel = j / NW, r = j - wsel * NW;
    src = ((wsel == 0) ? Wq : (wsel == 1) ? Wk : (wsel == 2) ? Wv : Wo) + r;
    dst = dstW + j;
  }
  float4 v = *reinterpret_cast<const float4*>(src);
  uint2 o;
  o.x = pk2(v.x, v.y); o.y = pk2(v.z, v.w);
  *reinterpret_cast<uint2*>(dst) = o;
}

// ---------------- GEMM: C[m,n] = sum_k A[m,k] * B[n,k]  (B stored [N][K]) ----
// R6-proven body. 1D grid, XCD-chunked bijective swizzle + n-fastest decompose.
// MODE 0: NB=9; scatters Q/K bf16 (Q scaled 0.125); V transposed VT[bh][d][t].
// MODE 1: NB=3; fp32 out + bias.
template <int MODE>
__global__ __launch_bounds__(256) void gemm_bt(
    const unsigned short* __restrict__ Ab,
    const unsigned short* __restrict__ Bw,
    unsigned short* __restrict__ Qb,
    unsigned short* __restrict__ Kb,
    unsigned short* __restrict__ VT,
    float* __restrict__ Co,
    const float* __restrict__ bias) {
  constexpr int NB = (MODE == 0) ? 9 : 3;          // n-blocks per m-panel
  constexpr int NWG = (MROWS / 128) * NB;          // 1728 / 576, both %8==0
  __shared__ __align__(16) short SH[32768];   // 64KB: 2 bufs x (A 16KB + B 16KB)
  const int tid = threadIdx.x;
  const int lane = tid & 63;
  const int w = tid >> 6;
  const int wm = w >> 1, wn = w & 1;
  // XCD-chunked bijective swizzle (m204): XCD x gets work [x*NWG/8,(x+1)*NWG/8)
  const int work = ((int)blockIdx.x % 8) * (NWG / 8) + (int)blockIdx.x / 8;
  const int m0 = (work / NB) * 128, n0 = (work % NB) * 128;
  const int l15 = lane & 15, lg = lane >> 4;
  char* shc = (char*)SH;

  auto stage = [&](int kt, int buf) {
    short* At = SH + buf * 16384;
    short* Bt = At + 8192;
    const int k0 = kt * 64;
#pragma unroll
    for (int j = 0; j < 4; ++j) {
      const int u = j * 256 + tid;
      const int row = u >> 3, un = u & 7;
      const int sw = (un ^ (row & 7)) * 8;
      const int ub = (j * 256 + (tid & ~63)) * 8;
      GLD16(Ab + (size_t)(m0 + row) * EMBED + k0 + sw, At + ub);
      GLD16(Bw + (size_t)(n0 + row) * EMBED + k0 + sw, Bt + ub);
    }
  };

  f32x4 acc[4][4];
#pragma unroll
  for (int i = 0; i < 4; ++i)
#pragma unroll
    for (int j = 0; j < 4; ++j) acc[i][j] = f32x4{0.f, 0.f, 0.f, 0.f};

  stage(0, 0);
  int cur = 0;
#pragma unroll 1
  for (int kt = 0; kt < 6; ++kt) {
    __syncthreads();                        // drains stage(kt) [vmcnt(0) auto]
    if (kt < 5) stage(kt + 1, cur ^ 1);     // next-tile loads fly under MFMA
    const char* Ac = shc + cur * 32768;
    const char* Bc = Ac + 16384;
#pragma unroll
    for (int kc = 0; kc < 2; ++kc) {
      bf16x8 af[4], bfr[4];
#pragma unroll
      for (int mt = 0; mt < 4; ++mt) {
        const int row = wm * 64 + mt * 16 + l15;
        af[mt] = *(const bf16x8*)(Ac + row * 128 + (((kc * 4 + lg) ^ (row & 7)) * 16));
      }
#pragma unroll
      for (int nt = 0; nt < 4; ++nt) {
        const int row = wn * 64 + nt * 16 + l15;
        bfr[nt] = *(const bf16x8*)(Bc + row * 128 + (((kc * 4 + lg) ^ (row & 7)) * 16));
      }
#pragma unroll
      for (int mt = 0; mt < 4; ++mt)
#pragma unroll
        for (int nt = 0; nt < 4; ++nt)
          acc[mt][nt] = __builtin_amdgcn_mfma_f32_16x16x32_bf16(
              af[mt], bfr[nt], acc[mt][nt], 0, 0, 0);
    }
    cur ^= 1;
  }

  if (MODE == 0 && n0 >= 768) {
    // ---- V blocks: transpose via LDS (reuse buf0, 32KB), write VT coalesced --
    const int b = m0 / SEQ, t0 = m0 - b * SEQ;
    __syncthreads();
#pragma unroll
    for (int mt = 0; mt < 4; ++mt)
#pragma unroll
      for (int nt = 0; nt < 4; ++nt)
#pragma unroll
        for (int r = 0; r < 4; ++r) {
          const int tl = wm * 64 + mt * 16 + lg * 4 + r;
          const int nl = wn * 64 + nt * 16 + l15;
          *(unsigned short*)(shc + nl * 256 + (((tl >> 3) ^ (nl & 7)) * 16) +
                             (tl & 7) * 2) = nbf(acc[mt][nt][r]);
        }
    __syncthreads();
#pragma unroll
    for (int j = 0; j < 8; ++j) {
      const int u = j * 256 + tid;
      const int row = u >> 4, un = u & 15;
      int4 vv = *(const int4*)(shc + row * 256 + ((un ^ (row & 7)) * 16));
      const int cg = (n0 - 768) + row;
      const int h = cg >> 6, d = cg & 63;
      *(int4*)(VT + ((size_t)(b * NHEAD + h) * HSZ + d) * SEQ + t0 + un * 8) = vv;
    }
    return;
  }

#pragma unroll
  for (int mt = 0; mt < 4; ++mt) {
#pragma unroll
    for (int nt = 0; nt < 4; ++nt) {
#pragma unroll
      for (int r = 0; r < 4; ++r) {
        const int m = m0 + wm * 64 + mt * 16 + lg * 4 + r;
        const int n = n0 + wn * 64 + nt * 16 + l15;
        const float v = acc[mt][nt][r];
        if (MODE == 0) {
          const int which = n / EMBED;   // 0=Q, 1=K here (V handled above)
          const int c = n - which * EMBED;
          const int h = c >> 6, d = c & 63;
          const int b = m / SEQ, t = m - b * SEQ;
          const size_t off = ((size_t)((b * NHEAD + h) * SEQ + t)) * HSZ + d;
          unsigned short* dstp = (which == 0) ? Qb : Kb;
          dstp[off] = nbf(which == 0 ? v * 0.125f : v);  // fold 1/sqrt(D) into Q
        } else {
          Co[(size_t)m * EMBED + n] = v + bias[n];
        }
      }
    }
  }
}

// ---------------- flash attention, causal, TRIPLE q-tiles per block ----------
// grid (8, 96): bh = (by/4)*8+bx (same-bh blocks share an XCD's L2).
// Block trip handles q-tiles {Q0,Q1,Q2}[trip]; one staged K/V tile feeds up
// to 3 R6-verbatim tile() calls. 768 blocks = exactly 3/CU (LDS 40KB).
__global__ __launch_bounds__(256, 3) void attn(const unsigned short* __restrict__ Qb,
                                               const unsigned short* __restrict__ Kb,
                                               const unsigned short* __restrict__ VT,
                                               unsigned short* __restrict__ AO) {
  __shared__ __align__(16) short Kt[2][64 * 64];   // [kv][d] swizzled, dbuf
  __shared__ __align__(16) short Vt[2][64 * 64];   // [d][kv] swizzled, dbuf
  __shared__ __align__(16) short Pl[4][16 * 64];   // per-wave P[q][kv] swizzled
  const int tid = threadIdx.x, lane = tid & 63, w = tid >> 6;
  const int l15 = lane & 15, lg = lane >> 4;
  const int trip = blockIdx.y & 3;
  const int bh = (blockIdx.y >> 2) * 8 + blockIdx.x;
  // balanced triples of q-tiles (each Σ(qt+1) = 19 or 20):
  const int q0t = trip;                                            // 0 1 2 3
  const int q1t = (trip == 3) ? 4 : trip + 5;                      // 5 6 7 4
  const int q2t = (trip == 0) ? 11 : (trip == 1) ? 10 : (trip == 2) ? 8 : 9;
  const size_t base = (size_t)bh * SEQ * HSZ;      // Qb/Kb [bh][t][d]
  char* pw = (char*)(&Pl[w][0]);

  bf16x8 qf0[2], qf1[2], qf2[2];
#pragma unroll
  for (int kc = 0; kc < 2; ++kc) {
    qf0[kc] = *(const bf16x8*)(Qb + base + (size_t)(q0t * 64 + w * 16 + l15) * HSZ +
                               kc * 32 + lg * 8);
    qf1[kc] = *(const bf16x8*)(Qb + base + (size_t)(q1t * 64 + w * 16 + l15) * HSZ +
                               kc * 32 + lg * 8);
    qf2[kc] = *(const bf16x8*)(Qb + base + (size_t)(q2t * 64 + w * 16 + l15) * HSZ +
                               kc * 32 + lg * 8);
  }

  f32x4 o0[4], o1[4], o2[4];
  float m0s = -3.0e38f, l0s = 0.f, m1s = -3.0e38f, l1s = 0.f;
  float m2s = -3.0e38f, l2s = 0.f;
#pragma unroll
  for (int nt = 0; nt < 4; ++nt) {
    o0[nt] = f32x4{0.f, 0.f, 0.f, 0.f};
    o1[nt] = f32x4{0.f, 0.f, 0.f, 0.f};
    o2[nt] = f32x4{0.f, 0.f, 0.f, 0.f};
  }

  auto stage = [&](int kt, int buf) {
#pragma unroll
    for (int j = 0; j < 2; ++j) {
      const int u = j * 256 + tid;
      const int row = u >> 3, un = u & 7;
      const int sw = (un ^ (row & 7)) * 8;
      const int ub = (j * 256 + (tid & ~63)) * 8;
      GLD16(Kb + base + (size_t)(kt * 64 + row) * HSZ + sw, &Kt[buf][ub]);
      GLD16(VT + base + (size_t)row * SEQ + kt * 64 + sw, &Vt[buf][ub]);
    }
  };

  // R6-verbatim tile: S^T = mfma(K,Q); lane owns q=l15; O^T += mfma(V^T,P)
  auto tile = [&](const bf16x8* qf, const bf16x8 kf[2][4], const char* Vc,
                  f32x4* o, float& m, float& l, bool diag) {
    f32x4 s[4];
#pragma unroll
    for (int nt = 0; nt < 4; ++nt) s[nt] = f32x4{0.f, 0.f, 0.f, 0.f};
    __builtin_amdgcn_s_setprio(1);
#pragma unroll
    for (int kc = 0; kc < 2; ++kc)
#pragma unroll
      for (int nt = 0; nt < 4; ++nt)
        s[nt] = __builtin_amdgcn_mfma_f32_16x16x32_bf16(kf[kc][nt], qf[kc], s[nt],
                                                        0, 0, 0);
    __builtin_amdgcn_s_setprio(0);
    if (diag) {
#pragma unroll
      for (int nt = 0; nt < 4; ++nt)
#pragma unroll
        for (int r = 0; r < 4; ++r)
          if (nt * 16 + lg * 4 + r > w * 16 + l15) s[nt][r] = -3.0e38f;
    }
    float mx = s[0][0];
#pragma unroll
    for (int nt = 0; nt < 4; ++nt)
#pragma unroll
      for (int r = 0; r < 4; ++r) mx = fmaxf(mx, s[nt][r]);
    mx = fmaxf(mx, __shfl_xor(mx, 16, 64));
    mx = fmaxf(mx, __shfl_xor(mx, 32, 64));
    const float mn = fmaxf(m, mx);
    const float alpha = __expf(m - mn);
    m = mn;
    float srow = 0.f;
#pragma unroll
    for (int nt = 0; nt < 4; ++nt)
#pragma unroll
      for (int r = 0; r < 4; ++r) {
        const float e = __expf(s[nt][r] - mn);
        s[nt][r] = e;
        srow += e;
      }
    srow += __shfl_xor(srow, 16, 64);
    srow += __shfl_xor(srow, 32, 64);
    l = l * alpha + srow;
#pragma unroll
    for (int nt = 0; nt < 4; ++nt) o[nt] *= alpha;
#pragma unroll
    for (int nt = 0; nt < 4; ++nt) {
      const int kv = nt * 16 + lg * 4;
      int2 pv;
      pv.x = (int)pk2(s[nt][0], s[nt][1]);
      pv.y = (int)pk2(s[nt][2], s[nt][3]);
      *(int2*)(pw + l15 * 128 + (((kv >> 3) ^ (l15 & 7)) * 16) + (kv & 7) * 2) = pv;
    }
    asm volatile("" ::: "memory");
    bf16x8 pf[2];
#pragma unroll
    for (int kc = 0; kc < 2; ++kc)
      pf[kc] = *(const bf16x8*)(pw + l15 * 128 + (((kc * 4 + lg) ^ (l15 & 7)) * 16));
    __builtin_amdgcn_s_setprio(1);
#pragma unroll
    for (int kc = 0; kc < 2; ++kc)
#pragma unroll
      for (int nt = 0; nt < 4; ++nt) {
        const int row = nt * 16 + l15;
        bf16x8 vf = *(const bf16x8*)(Vc + row * 128 +
                                     (((kc * 4 + lg) ^ (row & 7)) * 16));
        o[nt] = __builtin_amdgcn_mfma_f32_16x16x32_bf16(vf, pf[kc], o[nt], 0, 0, 0);
      }
    __builtin_amdgcn_s_setprio(0);
  };

  stage(0, 0);
  int cur = 0;
#pragma unroll 1
  for (int kt = 0; kt <= q2t; ++kt) {
    __syncthreads();                        // buf[cur] staged; buf[cur^1] free
    if (kt < q2t) stage(kt + 1, cur ^ 1);   // loads fly under compute
    const char* Kc = (const char*)Kt[cur];
    const char* Vc = (const char*)Vt[cur];
    bf16x8 kf[2][4];
#pragma unroll
    for (int kc = 0; kc < 2; ++kc)
#pragma unroll
      for (int nt = 0; nt < 4; ++nt) {
        const int row = nt * 16 + l15;
        kf[kc][nt] = *(const bf16x8*)(Kc + row * 128 +
                                      (((kc * 4 + lg) ^ (row & 7)) * 16));
      }
    tile(qf2, kf, Vc, o2, m2s, l2s, kt == q2t);
    if (kt <= q1t) tile(qf1, kf, Vc, o1, m1s, l1s, kt == q1t);
    if (kt <= q0t) tile(qf0, kf, Vc, o0, m0s, l0s, kt == q0t);
    cur ^= 1;
  }

  // epilogue: lane holds O[q=l15][d=nt*16+lg*4+r]; ushort4 stores x3
  const int bq = bh / NHEAD, h = bh - bq * NHEAD;
  const float inv0 = 1.f / l0s, inv1 = 1.f / l1s, inv2 = 1.f / l2s;
#pragma unroll
  for (int nt = 0; nt < 4; ++nt) {
    ushort4 s0, s1, s2;
    s0.x = nbf(o0[nt][0] * inv0); s0.y = nbf(o0[nt][1] * inv0);
    s0.z = nbf(o0[nt][2] * inv0); s0.w = nbf(o0[nt][3] * inv0);
    s1.x = nbf(o1[nt][0] * inv1); s1.y = nbf(o1[nt][1] * inv1);
    s1.z = nbf(o1[nt][2] * inv1); s1.w = nbf(o1[nt][3] * inv1);
    s2.x = nbf(o2[nt][0] * inv2); s2.y = nbf(o2[nt][1] * inv2);
    s2.z = nbf(o2[nt][2] * inv2); s2.w = nbf(o2[nt][3] * inv2);
    const int col = h * HSZ + nt * 16 + lg * 4;
    *(ushort4*)(AO + ((size_t)(bq * SEQ + q0t * 64 + w * 16 + l15)) * EMBED + col) = s0;
    *(ushort4*)(AO + ((size_t)(bq * SEQ + q1t * 64 + w * 16 + l15)) * EMBED + col) = s1;
    *(ushort4*)(AO + ((size_t)(bq * SEQ + q2t * 64 + w * 16 + l15)) * EMBED + col) = s2;
  }
}

extern "C" void kernel_launch(void* const* d_in, const int* in_sizes, int n_in,
                              void* d_out, int out_size, void* d_ws, size_t ws_size,
                              hipStream_t stream) {
  const float* X  = (const float*)d_in[0];
  const float* Wq = (const float*)d_in[1];
  const float* Wk = (const float*)d_in[2];
  const float* Wv = (const float*)d_in[3];
  const float* Wo = (const float*)d_in[4];
  const float* bo = (const float*)d_in[5];
  float* out = (float*)d_out;

  const size_t NW = (size_t)EMBED * EMBED;   // 147456
  const size_t NX = (size_t)MROWS * EMBED;   // 9437184
  unsigned short* ws    = (unsigned short*)d_ws;
  unsigned short* Wqkvb = ws;                // 3*NW
  unsigned short* Wob   = Wqkvb + 3 * NW;    // NW (contiguous after Wqkvb)
  unsigned short* XbAO  = Wob + NW;          // NX: Xb (pre-attn) then AO
  unsigned short* Qb    = XbAO + NX;         // NX  [B,H,T,D]
  unsigned short* Kb    = Qb + NX;           // NX  [B,H,T,D]
  unsigned short* VTb   = Kb + NX;           // NX  [B,H,D,T] (transposed V)
  // total: 4*NW + 4*NX ushorts = 76.7 MB of d_ws

  cvtAll<<<(int)((NX + 4 * NW) / 4 / 256), 256, 0, stream>>>(
      X, Wq, Wk, Wv, Wo, Wqkvb, XbAO);

  gemm_bt<0><<<(MROWS / 128) * 9, 256, 0, stream>>>(
      XbAO, Wqkvb, Qb, Kb, VTb, nullptr, nullptr);

  attn<<<dim3(8, 96), 256, 0, stream>>>(Qb, Kb, VTb, XbAO);

  gemm_bt<1><<<(MROWS / 128) * 3, 256, 0, stream>>>(
      XbAO, Wob, nullptr, nullptr, nullptr, out, bo);
}

// Round 16
// 102.105 us; speedup vs baseline: 1.2739x; 1.0181x over previous
//
#include <hip/hip_runtime.h>
#include <stdint.h>

#define EMBED 384
#define NHEAD 6
#define HSZ   64
#define BATCH 32
#define SEQ   768
#define MROWS (BATCH * SEQ)   // 24576
#define NTILE (SEQ / 64)      // 12

typedef __bf16 bf16x8 __attribute__((ext_vector_type(8)));
typedef float  f32x4  __attribute__((ext_vector_type(4)));

#define GLD16(gp, lp)                                                        \
  __builtin_amdgcn_global_load_lds(                                          \
      (const __attribute__((address_space(1))) void*)(gp),                   \
      (__attribute__((address_space(3))) void*)(lp), 16, 0, 0)

__device__ inline unsigned short nbf(float f) {   // native RNE convert
  union { __bf16 b; unsigned short s; } c; c.b = (__bf16)f; return c.s;
}
__device__ inline uint32_t pk2(float a, float b) { // -> v_cvt_pk_bf16_f32
  union { __bf16 b[2]; uint32_t u; } c;
  c.b[0] = (__bf16)a; c.b[1] = (__bf16)b; return c.u;
}

// ---------------- fused fp32 -> bf16 convert: X then Wq|Wk|Wv|Wo ------------
// Grid-stride (G11): 2048 blocks, ~5 float4 units per thread.
__global__ __launch_bounds__(256) void cvtAll(const float* __restrict__ X,
                                              const float* __restrict__ Wq,
                                              const float* __restrict__ Wk,
                                              const float* __restrict__ Wv,
                                              const float* __restrict__ Wo,
                                              unsigned short* __restrict__ dstW,
                                              unsigned short* __restrict__ dstX) {
  const int NX = MROWS * EMBED, NW = EMBED * EMBED;
  const int total = (NX + 4 * NW) / 4;
  for (int u = blockIdx.x * 256 + threadIdx.x; u < total; u += gridDim.x * 256) {
    const int i = u * 4;
    const float* src;
    unsigned short* dst;
    if (i < NX) {
      src = X + i; dst = dstX + i;
    } else {
      int j = i - NX;
      int wsel = j / NW, r = j - wsel * NW;
      src = ((wsel == 0) ? Wq : (wsel == 1) ? Wk : (wsel == 2) ? Wv : Wo) + r;
      dst = dstW + j;
    }
    float4 v = *reinterpret_cast<const float4*>(src);
    uint2 o;
    o.x = pk2(v.x, v.y); o.y = pk2(v.z, v.w);
    *reinterpret_cast<uint2*>(dst) = o;
  }
}

// ---------------- GEMM: C[m,n] = sum_k A[m,k] * B[n,k]  (B stored [N][K]) ----
// R6-proven body. 1D grid, XCD-chunked bijective swizzle + n-fastest decompose.
// MODE 0: NB=9; scatters Q/K bf16 (Q scaled 0.125); V transposed VT[bh][d][t].
// MODE 1: NB=3; fp32 out + bias.
template <int MODE>
__global__ __launch_bounds__(256) void gemm_bt(
    const unsigned short* __restrict__ Ab,
    const unsigned short* __restrict__ Bw,
    unsigned short* __restrict__ Qb,
    unsigned short* __restrict__ Kb,
    unsigned short* __restrict__ VT,
    float* __restrict__ Co,
    const float* __restrict__ bias) {
  constexpr int NB = (MODE == 0) ? 9 : 3;          // n-blocks per m-panel
  constexpr int NWG = (MROWS / 128) * NB;          // 1728 / 576, both %8==0
  __shared__ __align__(16) short SH[32768];   // 64KB: 2 bufs x (A 16KB + B 16KB)
  const int tid = threadIdx.x;
  const int lane = tid & 63;
  const int w = tid >> 6;
  const int wm = w >> 1, wn = w & 1;
  // XCD-chunked bijective swizzle (m204): XCD x gets work [x*NWG/8,(x+1)*NWG/8)
  const int work = ((int)blockIdx.x % 8) * (NWG / 8) + (int)blockIdx.x / 8;
  const int m0 = (work / NB) * 128, n0 = (work % NB) * 128;
  const int l15 = lane & 15, lg = lane >> 4;
  char* shc = (char*)SH;

  auto stage = [&](int kt, int buf) {
    short* At = SH + buf * 16384;
    short* Bt = At + 8192;
    const int k0 = kt * 64;
#pragma unroll
    for (int j = 0; j < 4; ++j) {
      const int u = j * 256 + tid;
      const int row = u >> 3, un = u & 7;
      const int sw = (un ^ (row & 7)) * 8;
      const int ub = (j * 256 + (tid & ~63)) * 8;
      GLD16(Ab + (size_t)(m0 + row) * EMBED + k0 + sw, At + ub);
      GLD16(Bw + (size_t)(n0 + row) * EMBED + k0 + sw, Bt + ub);
    }
  };

  f32x4 acc[4][4];
#pragma unroll
  for (int i = 0; i < 4; ++i)
#pragma unroll
    for (int j = 0; j < 4; ++j) acc[i][j] = f32x4{0.f, 0.f, 0.f, 0.f};

  stage(0, 0);
  int cur = 0;
#pragma unroll 1
  for (int kt = 0; kt < 6; ++kt) {
    __syncthreads();                        // drains stage(kt) [vmcnt(0) auto]
    if (kt < 5) stage(kt + 1, cur ^ 1);     // next-tile loads fly under MFMA
    const char* Ac = shc + cur * 32768;
    const char* Bc = Ac + 16384;
#pragma unroll
    for (int kc = 0; kc < 2; ++kc) {
      bf16x8 af[4], bfr[4];
#pragma unroll
      for (int mt = 0; mt < 4; ++mt) {
        const int row = wm * 64 + mt * 16 + l15;
        af[mt] = *(const bf16x8*)(Ac + row * 128 + (((kc * 4 + lg) ^ (row & 7)) * 16));
      }
#pragma unroll
      for (int nt = 0; nt < 4; ++nt) {
        const int row = wn * 64 + nt * 16 + l15;
        bfr[nt] = *(const bf16x8*)(Bc + row * 128 + (((kc * 4 + lg) ^ (row & 7)) * 16));
      }
#pragma unroll
      for (int mt = 0; mt < 4; ++mt)
#pragma unroll
        for (int nt = 0; nt < 4; ++nt)
          acc[mt][nt] = __builtin_amdgcn_mfma_f32_16x16x32_bf16(
              af[mt], bfr[nt], acc[mt][nt], 0, 0, 0);
    }
    cur ^= 1;
  }

  if (MODE == 0 && n0 >= 768) {
    // ---- V blocks: transpose via LDS (reuse buf0, 32KB), write VT coalesced --
    const int b = m0 / SEQ, t0 = m0 - b * SEQ;
    __syncthreads();
#pragma unroll
    for (int mt = 0; mt < 4; ++mt)
#pragma unroll
      for (int nt = 0; nt < 4; ++nt)
#pragma unroll
        for (int r = 0; r < 4; ++r) {
          const int tl = wm * 64 + mt * 16 + lg * 4 + r;
          const int nl = wn * 64 + nt * 16 + l15;
          *(unsigned short*)(shc + nl * 256 + (((tl >> 3) ^ (nl & 7)) * 16) +
                             (tl & 7) * 2) = nbf(acc[mt][nt][r]);
        }
    __syncthreads();
#pragma unroll
    for (int j = 0; j < 8; ++j) {
      const int u = j * 256 + tid;
      const int row = u >> 4, un = u & 15;
      int4 vv = *(const int4*)(shc + row * 256 + ((un ^ (row & 7)) * 16));
      const int cg = (n0 - 768) + row;
      const int h = cg >> 6, d = cg & 63;
      *(int4*)(VT + ((size_t)(b * NHEAD + h) * HSZ + d) * SEQ + t0 + un * 8) = vv;
    }
    return;
  }

  // block-uniform scatter bases (128-wide blocks straddle neither 384 nor 768)
  const int whichU = (MODE == 0) ? (n0 / EMBED) : 0;        // 0=Q, 1=K
  const int bU = m0 / SEQ;                                   // batch index
  const int tU = m0 - bU * SEQ;                              // seq base
#pragma unroll
  for (int mt = 0; mt < 4; ++mt) {
#pragma unroll
    for (int nt = 0; nt < 4; ++nt) {
#pragma unroll
      for (int r = 0; r < 4; ++r) {
        const int ml = wm * 64 + mt * 16 + lg * 4 + r;       // m offset in block
        const int n = n0 + wn * 64 + nt * 16 + l15;
        const float v = acc[mt][nt][r];
        if (MODE == 0) {
          const int c = n - whichU * EMBED;
          const int h = c >> 6, d = c & 63;
          const size_t off =
              ((size_t)((bU * NHEAD + h) * SEQ + tU + ml)) * HSZ + d;
          unsigned short* dstp = (whichU == 0) ? Qb : Kb;
          dstp[off] = nbf(whichU == 0 ? v * 0.125f : v);  // fold 1/sqrt(D) into Q
        } else {
          Co[(size_t)(m0 + ml) * EMBED + n] = v + bias[n];
        }
      }
    }
  }
}

// ---------------- flash attention, causal, TRIPLE q-tiles per block ----------
// grid (8, 96): bh = (by/4)*8+bx (same-bh blocks share an XCD's L2).
// Block trip handles q-tiles {Q0,Q1,Q2}[trip]; one staged K/V tile feeds up
// to 3 R6-verbatim tile() calls. 768 blocks = exactly 3/CU (LDS 40KB).
__global__ __launch_bounds__(256, 3) void attn(const unsigned short* __restrict__ Qb,
                                               const unsigned short* __restrict__ Kb,
                                               const unsigned short* __restrict__ VT,
                                               unsigned short* __restrict__ AO) {
  __shared__ __align__(16) short Kt[2][64 * 64];   // [kv][d] swizzled, dbuf
  __shared__ __align__(16) short Vt[2][64 * 64];   // [d][kv] swizzled, dbuf
  __shared__ __align__(16) short Pl[4][16 * 64];   // per-wave P[q][kv] swizzled
  const int tid = threadIdx.x, lane = tid & 63, w = tid >> 6;
  const int l15 = lane & 15, lg = lane >> 4;
  const int trip = blockIdx.y & 3;
  const int bh = (blockIdx.y >> 2) * 8 + blockIdx.x;
  // balanced triples of q-tiles (each Σ(qt+1) = 19 or 20):
  const int q0t = trip;                                            // 0 1 2 3
  const int q1t = (trip == 3) ? 4 : trip + 5;                      // 5 6 7 4
  const int q2t = (trip == 0) ? 11 : (trip == 1) ? 10 : (trip == 2) ? 8 : 9;
  const size_t base = (size_t)bh * SEQ * HSZ;      // Qb/Kb [bh][t][d]
  char* pw = (char*)(&Pl[w][0]);

  bf16x8 qf0[2], qf1[2], qf2[2];
#pragma unroll
  for (int kc = 0; kc < 2; ++kc) {
    qf0[kc] = *(const bf16x8*)(Qb + base + (size_t)(q0t * 64 + w * 16 + l15) * HSZ +
                               kc * 32 + lg * 8);
    qf1[kc] = *(const bf16x8*)(Qb + base + (size_t)(q1t * 64 + w * 16 + l15) * HSZ +
                               kc * 32 + lg * 8);
    qf2[kc] = *(const bf16x8*)(Qb + base + (size_t)(q2t * 64 + w * 16 + l15) * HSZ +
                               kc * 32 + lg * 8);
  }

  f32x4 o0[4], o1[4], o2[4];
  float m0s = -3.0e38f, l0s = 0.f, m1s = -3.0e38f, l1s = 0.f;
  float m2s = -3.0e38f, l2s = 0.f;
#pragma unroll
  for (int nt = 0; nt < 4; ++nt) {
    o0[nt] = f32x4{0.f, 0.f, 0.f, 0.f};
    o1[nt] = f32x4{0.f, 0.f, 0.f, 0.f};
    o2[nt] = f32x4{0.f, 0.f, 0.f, 0.f};
  }

  auto stage = [&](int kt, int buf) {
#pragma unroll
    for (int j = 0; j < 2; ++j) {
      const int u = j * 256 + tid;
      const int row = u >> 3, un = u & 7;
      const int sw = (un ^ (row & 7)) * 8;
      const int ub = (j * 256 + (tid & ~63)) * 8;
      GLD16(Kb + base + (size_t)(kt * 64 + row) * HSZ + sw, &Kt[buf][ub]);
      GLD16(VT + base + (size_t)row * SEQ + kt * 64 + sw, &Vt[buf][ub]);
    }
  };

  // R6-verbatim tile: S^T = mfma(K,Q); lane owns q=l15; O^T += mfma(V^T,P)
  auto tile = [&](const bf16x8* qf, const bf16x8 kf[2][4], const char* Vc,
                  f32x4* o, float& m, float& l, bool diag) {
    f32x4 s[4];
#pragma unroll
    for (int nt = 0; nt < 4; ++nt) s[nt] = f32x4{0.f, 0.f, 0.f, 0.f};
    __builtin_amdgcn_s_setprio(1);
#pragma unroll
    for (int kc = 0; kc < 2; ++kc)
#pragma unroll
      for (int nt = 0; nt < 4; ++nt)
        s[nt] = __builtin_amdgcn_mfma_f32_16x16x32_bf16(kf[kc][nt], qf[kc], s[nt],
                                                        0, 0, 0);
    __builtin_amdgcn_s_setprio(0);
    if (diag) {
#pragma unroll
      for (int nt = 0; nt < 4; ++nt)
#pragma unroll
        for (int r = 0; r < 4; ++r)
          if (nt * 16 + lg * 4 + r > w * 16 + l15) s[nt][r] = -3.0e38f;
    }
    float mx = s[0][0];
#pragma unroll
    for (int nt = 0; nt < 4; ++nt)
#pragma unroll
      for (int r = 0; r < 4; ++r) mx = fmaxf(mx, s[nt][r]);
    mx = fmaxf(mx, __shfl_xor(mx, 16, 64));
    mx = fmaxf(mx, __shfl_xor(mx, 32, 64));
    const float mn = fmaxf(m, mx);
    const float alpha = __expf(m - mn);
    m = mn;
    float srow = 0.f;
#pragma unroll
    for (int nt = 0; nt < 4; ++nt)
#pragma unroll
      for (int r = 0; r < 4; ++r) {
        const float e = __expf(s[nt][r] - mn);
        s[nt][r] = e;
        srow += e;
      }
    srow += __shfl_xor(srow, 16, 64);
    srow += __shfl_xor(srow, 32, 64);
    l = l * alpha + srow;
#pragma unroll
    for (int nt = 0; nt < 4; ++nt) o[nt] *= alpha;
#pragma unroll
    for (int nt = 0; nt < 4; ++nt) {
      const int kv = nt * 16 + lg * 4;
      int2 pv;
      pv.x = (int)pk2(s[nt][0], s[nt][1]);
      pv.y = (int)pk2(s[nt][2], s[nt][3]);
      *(int2*)(pw + l15 * 128 + (((kv >> 3) ^ (l15 & 7)) * 16) + (kv & 7) * 2) = pv;
    }
    asm volatile("" ::: "memory");
    bf16x8 pf[2];
#pragma unroll
    for (int kc = 0; kc < 2; ++kc)
      pf[kc] = *(const bf16x8*)(pw + l15 * 128 + (((kc * 4 + lg) ^ (l15 & 7)) * 16));
    __builtin_amdgcn_s_setprio(1);
#pragma unroll
    for (int kc = 0; kc < 2; ++kc)
#pragma unroll
      for (int nt = 0; nt < 4; ++nt) {
        const int row = nt * 16 + l15;
        bf16x8 vf = *(const bf16x8*)(Vc + row * 128 +
                                     (((kc * 4 + lg) ^ (row & 7)) * 16));
        o[nt] = __builtin_amdgcn_mfma_f32_16x16x32_bf16(vf, pf[kc], o[nt], 0, 0, 0);
      }
    __builtin_amdgcn_s_setprio(0);
  };

  stage(0, 0);
  int cur = 0;
#pragma unroll 1
  for (int kt = 0; kt <= q2t; ++kt) {
    __syncthreads();                        // buf[cur] staged; buf[cur^1] free
    if (kt < q2t) stage(kt + 1, cur ^ 1);   // loads fly under compute
    const char* Kc = (const char*)Kt[cur];
    const char* Vc = (const char*)Vt[cur];
    bf16x8 kf[2][4];
#pragma unroll
    for (int kc = 0; kc < 2; ++kc)
#pragma unroll
      for (int nt = 0; nt < 4; ++nt) {
        const int row = nt * 16 + l15;
        kf[kc][nt] = *(const bf16x8*)(Kc + row * 128 +
                                      (((kc * 4 + lg) ^ (row & 7)) * 16));
      }
    tile(qf2, kf, Vc, o2, m2s, l2s, kt == q2t);
    if (kt <= q1t) tile(qf1, kf, Vc, o1, m1s, l1s, kt == q1t);
    if (kt <= q0t) tile(qf0, kf, Vc, o0, m0s, l0s, kt == q0t);
    cur ^= 1;
  }

  // epilogue: lane holds O[q=l15][d=nt*16+lg*4+r]; ushort4 stores x3
  const int bq = bh / NHEAD, h = bh - bq * NHEAD;
  const float inv0 = 1.f / l0s, inv1 = 1.f / l1s, inv2 = 1.f / l2s;
#pragma unroll
  for (int nt = 0; nt < 4; ++nt) {
    ushort4 s0, s1, s2;
    s0.x = nbf(o0[nt][0] * inv0); s0.y = nbf(o0[nt][1] * inv0);
    s0.z = nbf(o0[nt][2] * inv0); s0.w = nbf(o0[nt][3] * inv0);
    s1.x = nbf(o1[nt][0] * inv1); s1.y = nbf(o1[nt][1] * inv1);
    s1.z = nbf(o1[nt][2] * inv1); s1.w = nbf(o1[nt][3] * inv1);
    s2.x = nbf(o2[nt][0] * inv2); s2.y = nbf(o2[nt][1] * inv2);
    s2.z = nbf(o2[nt][2] * inv2); s2.w = nbf(o2[nt][3] * inv2);
    const int col = h * HSZ + nt * 16 + lg * 4;
    *(ushort4*)(AO + ((size_t)(bq * SEQ + q0t * 64 + w * 16 + l15)) * EMBED + col) = s0;
    *(ushort4*)(AO + ((size_t)(bq * SEQ + q1t * 64 + w * 16 + l15)) * EMBED + col) = s1;
    *(ushort4*)(AO + ((size_t)(bq * SEQ + q2t * 64 + w * 16 + l15)) * EMBED + col) = s2;
  }
}

extern "C" void kernel_launch(void* const* d_in, const int* in_sizes, int n_in,
                              void* d_out, int out_size, void* d_ws, size_t ws_size,
                              hipStream_t stream) {
  const float* X  = (const float*)d_in[0];
  const float* Wq = (const float*)d_in[1];
  const float* Wk = (const float*)d_in[2];
  const float* Wv = (const float*)d_in[3];
  const float* Wo = (const float*)d_in[4];
  const float* bo = (const float*)d_in[5];
  float* out = (float*)d_out;

  const size_t NW = (size_t)EMBED * EMBED;   // 147456
  const size_t NX = (size_t)MROWS * EMBED;   // 9437184
  unsigned short* ws    = (unsigned short*)d_ws;
  unsigned short* Wqkvb = ws;                // 3*NW
  unsigned short* Wob   = Wqkvb + 3 * NW;    // NW (contiguous after Wqkvb)
  unsigned short* XbAO  = Wob + NW;          // NX: Xb (pre-attn) then AO
  unsigned short* Qb    = XbAO + NX;         // NX  [B,H,T,D]
  unsigned short* Kb    = Qb + NX;           // NX  [B,H,T,D]
  unsigned short* VTb   = Kb + NX;           // NX  [B,H,D,T] (transposed V)
  // total: 4*NW + 4*NX ushorts = 76.7 MB of d_ws

  cvtAll<<<2048, 256, 0, stream>>>(X, Wq, Wk, Wv, Wo, Wqkvb, XbAO);

  gemm_bt<0><<<(MROWS / 128) * 9, 256, 0, stream>>>(
      XbAO, Wqkvb, Qb, Kb, VTb, nullptr, nullptr);

  attn<<<dim3(8, 96), 256, 0, stream>>>(Qb, Kb, VTb, XbAO);

  gemm_bt<1><<<(MROWS / 128) * 3, 256, 0, stream>>>(
      XbAO, Wob, nullptr, nullptr, nullptr, out, bo);
}

// Round 17
// 100.000 us; speedup vs baseline: 1.3007x; 1.0210x over previous
//
#include <hip/hip_runtime.h>
#include <stdint.h>

#define EMBED 384
#define NHEAD 6
#define HSZ   64
#define BATCH 32
#define SEQ   768
#define MROWS (BATCH * SEQ)   // 24576
#define NTILE (SEQ / 64)      // 12

typedef __bf16 bf16x8 __attribute__((ext_vector_type(8)));
typedef float  f32x4  __attribute__((ext_vector_type(4)));

#define GLD16(gp, lp)                                                        \
  __builtin_amdgcn_global_load_lds(                                          \
      (const __attribute__((address_space(1))) void*)(gp),                   \
      (__attribute__((address_space(3))) void*)(lp), 16, 0, 0)

#define QSCALE 0.18033688011112042f   /* 0.125 * log2(e): exp2-domain scores */

__device__ inline unsigned short nbf(float f) {   // native RNE convert
  union { __bf16 b; unsigned short s; } c; c.b = (__bf16)f; return c.s;
}
__device__ inline uint32_t pk2(float a, float b) { // -> v_cvt_pk_bf16_f32
  union { __bf16 b[2]; uint32_t u; } c;
  c.b[0] = (__bf16)a; c.b[1] = (__bf16)b; return c.u;
}

// ---------------- fused fp32 -> bf16 convert: X then Wq|Wk|Wv|Wo ------------
// Grid-stride (G11): 2048 blocks, ~5 float4 units per thread.
__global__ __launch_bounds__(256) void cvtAll(const float* __restrict__ X,
                                              const float* __restrict__ Wq,
                                              const float* __restrict__ Wk,
                                              const float* __restrict__ Wv,
                                              const float* __restrict__ Wo,
                                              unsigned short* __restrict__ dstW,
                                              unsigned short* __restrict__ dstX) {
  const int NX = MROWS * EMBED, NW = EMBED * EMBED;
  const int total = (NX + 4 * NW) / 4;
  for (int u = blockIdx.x * 256 + threadIdx.x; u < total; u += gridDim.x * 256) {
    const int i = u * 4;
    const float* src;
    unsigned short* dst;
    if (i < NX) {
      src = X + i; dst = dstX + i;
    } else {
      int j = i - NX;
      int wsel = j / NW, r = j - wsel * NW;
      src = ((wsel == 0) ? Wq : (wsel == 1) ? Wk : (wsel == 2) ? Wv : Wo) + r;
      dst = dstW + j;
    }
    float4 v = *reinterpret_cast<const float4*>(src);
    uint2 o;
    o.x = pk2(v.x, v.y); o.y = pk2(v.z, v.w);
    *reinterpret_cast<uint2*>(dst) = o;
  }
}

// ---------------- GEMM: C[m,n] = sum_k A[m,k] * B[n,k]  (B stored [N][K]) ----
// R6-proven body. 1D grid, XCD-chunked bijective swizzle + n-fastest decompose.
// MODE 0: NB=9; scatters Q/K bf16 (Q scaled QSCALE); V transposed VT[bh][d][t].
// MODE 1: NB=3; fp32 out + bias.
template <int MODE>
__global__ __launch_bounds__(256) void gemm_bt(
    const unsigned short* __restrict__ Ab,
    const unsigned short* __restrict__ Bw,
    unsigned short* __restrict__ Qb,
    unsigned short* __restrict__ Kb,
    unsigned short* __restrict__ VT,
    float* __restrict__ Co,
    const float* __restrict__ bias) {
  constexpr int NB = (MODE == 0) ? 9 : 3;          // n-blocks per m-panel
  constexpr int NWG = (MROWS / 128) * NB;          // 1728 / 576, both %8==0
  __shared__ __align__(16) short SH[32768];   // 64KB: 2 bufs x (A 16KB + B 16KB)
  const int tid = threadIdx.x;
  const int lane = tid & 63;
  const int w = tid >> 6;
  const int wm = w >> 1, wn = w & 1;
  // XCD-chunked bijective swizzle (m204): XCD x gets work [x*NWG/8,(x+1)*NWG/8)
  const int work = ((int)blockIdx.x % 8) * (NWG / 8) + (int)blockIdx.x / 8;
  const int m0 = (work / NB) * 128, n0 = (work % NB) * 128;
  const int l15 = lane & 15, lg = lane >> 4;
  char* shc = (char*)SH;

  auto stage = [&](int kt, int buf) {
    short* At = SH + buf * 16384;
    short* Bt = At + 8192;
    const int k0 = kt * 64;
#pragma unroll
    for (int j = 0; j < 4; ++j) {
      const int u = j * 256 + tid;
      const int row = u >> 3, un = u & 7;
      const int sw = (un ^ (row & 7)) * 8;
      const int ub = (j * 256 + (tid & ~63)) * 8;
      GLD16(Ab + (size_t)(m0 + row) * EMBED + k0 + sw, At + ub);
      GLD16(Bw + (size_t)(n0 + row) * EMBED + k0 + sw, Bt + ub);
    }
  };

  f32x4 acc[4][4];
#pragma unroll
  for (int i = 0; i < 4; ++i)
#pragma unroll
    for (int j = 0; j < 4; ++j) acc[i][j] = f32x4{0.f, 0.f, 0.f, 0.f};

  stage(0, 0);
  int cur = 0;
#pragma unroll 1
  for (int kt = 0; kt < 6; ++kt) {
    __syncthreads();                        // drains stage(kt) [vmcnt(0) auto]
    if (kt < 5) stage(kt + 1, cur ^ 1);     // next-tile loads fly under MFMA
    const char* Ac = shc + cur * 32768;
    const char* Bc = Ac + 16384;
#pragma unroll
    for (int kc = 0; kc < 2; ++kc) {
      bf16x8 af[4], bfr[4];
#pragma unroll
      for (int mt = 0; mt < 4; ++mt) {
        const int row = wm * 64 + mt * 16 + l15;
        af[mt] = *(const bf16x8*)(Ac + row * 128 + (((kc * 4 + lg) ^ (row & 7)) * 16));
      }
#pragma unroll
      for (int nt = 0; nt < 4; ++nt) {
        const int row = wn * 64 + nt * 16 + l15;
        bfr[nt] = *(const bf16x8*)(Bc + row * 128 + (((kc * 4 + lg) ^ (row & 7)) * 16));
      }
#pragma unroll
      for (int mt = 0; mt < 4; ++mt)
#pragma unroll
        for (int nt = 0; nt < 4; ++nt)
          acc[mt][nt] = __builtin_amdgcn_mfma_f32_16x16x32_bf16(
              af[mt], bfr[nt], acc[mt][nt], 0, 0, 0);
    }
    cur ^= 1;
  }

  if (MODE == 0 && n0 >= 768) {
    // ---- V blocks: transpose via LDS (reuse buf0, 32KB), write VT coalesced --
    const int b = m0 / SEQ, t0 = m0 - b * SEQ;
    __syncthreads();
#pragma unroll
    for (int mt = 0; mt < 4; ++mt)
#pragma unroll
      for (int nt = 0; nt < 4; ++nt)
#pragma unroll
        for (int r = 0; r < 4; ++r) {
          const int tl = wm * 64 + mt * 16 + lg * 4 + r;
          const int nl = wn * 64 + nt * 16 + l15;
          *(unsigned short*)(shc + nl * 256 + (((tl >> 3) ^ (nl & 7)) * 16) +
                             (tl & 7) * 2) = nbf(acc[mt][nt][r]);
        }
    __syncthreads();
#pragma unroll
    for (int j = 0; j < 8; ++j) {
      const int u = j * 256 + tid;
      const int row = u >> 4, un = u & 15;
      int4 vv = *(const int4*)(shc + row * 256 + ((un ^ (row & 7)) * 16));
      const int cg = (n0 - 768) + row;
      const int h = cg >> 6, d = cg & 63;
      *(int4*)(VT + ((size_t)(b * NHEAD + h) * HSZ + d) * SEQ + t0 + un * 8) = vv;
    }
    return;
  }

  // block-uniform scatter bases (128-wide blocks straddle neither 384 nor 768)
  const int whichU = (MODE == 0) ? (n0 / EMBED) : 0;        // 0=Q, 1=K
  const int bU = m0 / SEQ;                                   // batch index
  const int tU = m0 - bU * SEQ;                              // seq base
#pragma unroll
  for (int mt = 0; mt < 4; ++mt) {
#pragma unroll
    for (int nt = 0; nt < 4; ++nt) {
#pragma unroll
      for (int r = 0; r < 4; ++r) {
        const int ml = wm * 64 + mt * 16 + lg * 4 + r;       // m offset in block
        const int n = n0 + wn * 64 + nt * 16 + l15;
        const float v = acc[mt][nt][r];
        if (MODE == 0) {
          const int c = n - whichU * EMBED;
          const int h = c >> 6, d = c & 63;
          const size_t off =
              ((size_t)((bU * NHEAD + h) * SEQ + tU + ml)) * HSZ + d;
          unsigned short* dstp = (whichU == 0) ? Qb : Kb;
          dstp[off] = nbf(whichU == 0 ? v * QSCALE : v);  // exp2-domain Q scale
        } else {
          Co[(size_t)(m0 + ml) * EMBED + n] = v + bias[n];
        }
      }
    }
  }
}

// ---------------- flash attention, causal, TRIPLE q-tiles per block ----------
// grid (8, 96): bh = (by/4)*8+bx (same-bh blocks share an XCD's L2).
// Block trip handles q-tiles {Q0,Q1,Q2}[trip]; one staged K/V tile feeds up
// to 3 tile() calls. 768 blocks = exactly 3/CU (LDS 40KB).
// Scores arrive pre-scaled by log2(e): softmax uses raw v_exp (2^x) — the
// ONLY delta vs R16's tile body (zero liveness change; R13/R14 remat lesson).
__global__ __launch_bounds__(256, 3) void attn(const unsigned short* __restrict__ Qb,
                                               const unsigned short* __restrict__ Kb,
                                               const unsigned short* __restrict__ VT,
                                               unsigned short* __restrict__ AO) {
  __shared__ __align__(16) short Kt[2][64 * 64];   // [kv][d] swizzled, dbuf
  __shared__ __align__(16) short Vt[2][64 * 64];   // [d][kv] swizzled, dbuf
  __shared__ __align__(16) short Pl[4][16 * 64];   // per-wave P[q][kv] swizzled
  const int tid = threadIdx.x, lane = tid & 63, w = tid >> 6;
  const int l15 = lane & 15, lg = lane >> 4;
  const int trip = blockIdx.y & 3;
  const int bh = (blockIdx.y >> 2) * 8 + blockIdx.x;
  // balanced triples of q-tiles (each Σ(qt+1) = 19 or 20):
  const int q0t = trip;                                            // 0 1 2 3
  const int q1t = (trip == 3) ? 4 : trip + 5;                      // 5 6 7 4
  const int q2t = (trip == 0) ? 11 : (trip == 1) ? 10 : (trip == 2) ? 8 : 9;
  const size_t base = (size_t)bh * SEQ * HSZ;      // Qb/Kb [bh][t][d]
  char* pw = (char*)(&Pl[w][0]);

  bf16x8 qf0[2], qf1[2], qf2[2];
#pragma unroll
  for (int kc = 0; kc < 2; ++kc) {
    qf0[kc] = *(const bf16x8*)(Qb + base + (size_t)(q0t * 64 + w * 16 + l15) * HSZ +
                               kc * 32 + lg * 8);
    qf1[kc] = *(const bf16x8*)(Qb + base + (size_t)(q1t * 64 + w * 16 + l15) * HSZ +
                               kc * 32 + lg * 8);
    qf2[kc] = *(const bf16x8*)(Qb + base + (size_t)(q2t * 64 + w * 16 + l15) * HSZ +
                               kc * 32 + lg * 8);
  }

  f32x4 o0[4], o1[4], o2[4];
  float m0s = -3.0e38f, l0s = 0.f, m1s = -3.0e38f, l1s = 0.f;
  float m2s = -3.0e38f, l2s = 0.f;
#pragma unroll
  for (int nt = 0; nt < 4; ++nt) {
    o0[nt] = f32x4{0.f, 0.f, 0.f, 0.f};
    o1[nt] = f32x4{0.f, 0.f, 0.f, 0.f};
    o2[nt] = f32x4{0.f, 0.f, 0.f, 0.f};
  }

  auto stage = [&](int kt, int buf) {
#pragma unroll
    for (int j = 0; j < 2; ++j) {
      const int u = j * 256 + tid;
      const int row = u >> 3, un = u & 7;
      const int sw = (un ^ (row & 7)) * 8;
      const int ub = (j * 256 + (tid & ~63)) * 8;
      GLD16(Kb + base + (size_t)(kt * 64 + row) * HSZ + sw, &Kt[buf][ub]);
      GLD16(VT + base + (size_t)row * SEQ + kt * 64 + sw, &Vt[buf][ub]);
    }
  };

  // R6-verbatim tile except exp->exp2: S^T = mfma(K,Q); lane owns q=l15
  auto tile = [&](const bf16x8* qf, const bf16x8 kf[2][4], const char* Vc,
                  f32x4* o, float& m, float& l, bool diag) {
    f32x4 s[4];
#pragma unroll
    for (int nt = 0; nt < 4; ++nt) s[nt] = f32x4{0.f, 0.f, 0.f, 0.f};
    __builtin_amdgcn_s_setprio(1);
#pragma unroll
    for (int kc = 0; kc < 2; ++kc)
#pragma unroll
      for (int nt = 0; nt < 4; ++nt)
        s[nt] = __builtin_amdgcn_mfma_f32_16x16x32_bf16(kf[kc][nt], qf[kc], s[nt],
                                                        0, 0, 0);
    __builtin_amdgcn_s_setprio(0);
    if (diag) {
#pragma unroll
      for (int nt = 0; nt < 4; ++nt)
#pragma unroll
        for (int r = 0; r < 4; ++r)
          if (nt * 16 + lg * 4 + r > w * 16 + l15) s[nt][r] = -3.0e38f;
    }
    float mx = s[0][0];
#pragma unroll
    for (int nt = 0; nt < 4; ++nt)
#pragma unroll
      for (int r = 0; r < 4; ++r) mx = fmaxf(mx, s[nt][r]);
    mx = fmaxf(mx, __shfl_xor(mx, 16, 64));
    mx = fmaxf(mx, __shfl_xor(mx, 32, 64));
    const float mn = fmaxf(m, mx);
    const float alpha = __builtin_amdgcn_exp2f(m - mn);
    m = mn;
    float srow = 0.f;
#pragma unroll
    for (int nt = 0; nt < 4; ++nt)
#pragma unroll
      for (int r = 0; r < 4; ++r) {
        const float e = __builtin_amdgcn_exp2f(s[nt][r] - mn);
        s[nt][r] = e;
        srow += e;
      }
    srow += __shfl_xor(srow, 16, 64);
    srow += __shfl_xor(srow, 32, 64);
    l = l * alpha + srow;
#pragma unroll
    for (int nt = 0; nt < 4; ++nt) o[nt] *= alpha;
#pragma unroll
    for (int nt = 0; nt < 4; ++nt) {
      const int kv = nt * 16 + lg * 4;
      int2 pv;
      pv.x = (int)pk2(s[nt][0], s[nt][1]);
      pv.y = (int)pk2(s[nt][2], s[nt][3]);
      *(int2*)(pw + l15 * 128 + (((kv >> 3) ^ (l15 & 7)) * 16) + (kv & 7) * 2) = pv;
    }
    asm volatile("" ::: "memory");
    bf16x8 pf[2];
#pragma unroll
    for (int kc = 0; kc < 2; ++kc)
      pf[kc] = *(const bf16x8*)(pw + l15 * 128 + (((kc * 4 + lg) ^ (l15 & 7)) * 16));
    __builtin_amdgcn_s_setprio(1);
#pragma unroll
    for (int kc = 0; kc < 2; ++kc)
#pragma unroll
      for (int nt = 0; nt < 4; ++nt) {
        const int row = nt * 16 + l15;
        bf16x8 vf = *(const bf16x8*)(Vc + row * 128 +
                                     (((kc * 4 + lg) ^ (row & 7)) * 16));
        o[nt] = __builtin_amdgcn_mfma_f32_16x16x32_bf16(vf, pf[kc], o[nt], 0, 0, 0);
      }
    __builtin_amdgcn_s_setprio(0);
  };

  stage(0, 0);
  int cur = 0;
#pragma unroll 1
  for (int kt = 0; kt <= q2t; ++kt) {
    __syncthreads();                        // buf[cur] staged; buf[cur^1] free
    if (kt < q2t) stage(kt + 1, cur ^ 1);   // loads fly under compute
    const char* Kc = (const char*)Kt[cur];
    const char* Vc = (const char*)Vt[cur];
    bf16x8 kf[2][4];
#pragma unroll
    for (int kc = 0; kc < 2; ++kc)
#pragma unroll
      for (int nt = 0; nt < 4; ++nt) {
        const int row = nt * 16 + l15;
        kf[kc][nt] = *(const bf16x8*)(Kc + row * 128 +
                                      (((kc * 4 + lg) ^ (row & 7)) * 16));
      }
    tile(qf2, kf, Vc, o2, m2s, l2s, kt == q2t);
    if (kt <= q1t) tile(qf1, kf, Vc, o1, m1s, l1s, kt == q1t);
    if (kt <= q0t) tile(qf0, kf, Vc, o0, m0s, l0s, kt == q0t);
    cur ^= 1;
  }

  // epilogue: lane holds O[q=l15][d=nt*16+lg*4+r]; ushort4 stores x3
  const int bq = bh / NHEAD, h = bh - bq * NHEAD;
  const float inv0 = 1.f / l0s, inv1 = 1.f / l1s, inv2 = 1.f / l2s;
#pragma unroll
  for (int nt = 0; nt < 4; ++nt) {
    ushort4 s0, s1, s2;
    s0.x = nbf(o0[nt][0] * inv0); s0.y = nbf(o0[nt][1] * inv0);
    s0.z = nbf(o0[nt][2] * inv0); s0.w = nbf(o0[nt][3] * inv0);
    s1.x = nbf(o1[nt][0] * inv1); s1.y = nbf(o1[nt][1] * inv1);
    s1.z = nbf(o1[nt][2] * inv1); s1.w = nbf(o1[nt][3] * inv1);
    s2.x = nbf(o2[nt][0] * inv2); s2.y = nbf(o2[nt][1] * inv2);
    s2.z = nbf(o2[nt][2] * inv2); s2.w = nbf(o2[nt][3] * inv2);
    const int col = h * HSZ + nt * 16 + lg * 4;
    *(ushort4*)(AO + ((size_t)(bq * SEQ + q0t * 64 + w * 16 + l15)) * EMBED + col) = s0;
    *(ushort4*)(AO + ((size_t)(bq * SEQ + q1t * 64 + w * 16 + l15)) * EMBED + col) = s1;
    *(ushort4*)(AO + ((size_t)(bq * SEQ + q2t * 64 + w * 16 + l15)) * EMBED + col) = s2;
  }
}

extern "C" void kernel_launch(void* const* d_in, const int* in_sizes, int n_in,
                              void* d_out, int out_size, void* d_ws, size_t ws_size,
                              hipStream_t stream) {
  const float* X  = (const float*)d_in[0];
  const float* Wq = (const float*)d_in[1];
  const float* Wk = (const float*)d_in[2];
  const float* Wv = (const float*)d_in[3];
  const float* Wo = (const float*)d_in[4];
  const float* bo = (const float*)d_in[5];
  float* out = (float*)d_out;

  const size_t NW = (size_t)EMBED * EMBED;   // 147456
  const size_t NX = (size_t)MROWS * EMBED;   // 9437184
  unsigned short* ws    = (unsigned short*)d_ws;
  unsigned short* Wqkvb = ws;                // 3*NW
  unsigned short* Wob   = Wqkvb + 3 * NW;    // NW (contiguous after Wqkvb)
  unsigned short* XbAO  = Wob + NW;          // NX: Xb (pre-attn) then AO
  unsigned short* Qb    = XbAO + NX;         // NX  [B,H,T,D]
  unsigned short* Kb    = Qb + NX;           // NX  [B,H,T,D]
  unsigned short* VTb   = Kb + NX;           // NX  [B,H,D,T] (transposed V)
  // total: 4*NW + 4*NX ushorts = 76.7 MB of d_ws

  cvtAll<<<2048, 256, 0, stream>>>(X, Wq, Wk, Wv, Wo, Wqkvb, XbAO);

  gemm_bt<0><<<(MROWS / 128) * 9, 256, 0, stream>>>(
      XbAO, Wqkvb, Qb, Kb, VTb, nullptr, nullptr);

  attn<<<dim3(8, 96), 256, 0, stream>>>(Qb, Kb, VTb, XbAO);

  gemm_bt<1><<<(MROWS / 128) * 3, 256, 0, stream>>>(
      XbAO, Wob, nullptr, nullptr, nullptr, out, bo);
}

// Round 18
// 99.442 us; speedup vs baseline: 1.3080x; 1.0056x over previous
//
#include <hip/hip_runtime.h>
#include <stdint.h>

#define EMBED 384
#define NHEAD 6
#define HSZ   64
#define BATCH 32
#define SEQ   768
#define MROWS (BATCH * SEQ)   // 24576
#define NTILE (SEQ / 64)      // 12

typedef __bf16 bf16x8 __attribute__((ext_vector_type(8)));
typedef float  f32x4  __attribute__((ext_vector_type(4)));

#define GLD16(gp, lp)                                                        \
  __builtin_amdgcn_global_load_lds(                                          \
      (const __attribute__((address_space(1))) void*)(gp),                   \
      (__attribute__((address_space(3))) void*)(lp), 16, 0, 0)

#define QSCALE 0.18033688011112042f   /* 0.125 * log2(e): exp2-domain scores */

__device__ inline unsigned short nbf(float f) {   // native RNE convert
  union { __bf16 b; unsigned short s; } c; c.b = (__bf16)f; return c.s;
}
__device__ inline uint32_t pk2(float a, float b) { // -> v_cvt_pk_bf16_f32
  union { __bf16 b[2]; uint32_t u; } c;
  c.b[0] = (__bf16)a; c.b[1] = (__bf16)b; return c.u;
}

// ---------------- fused fp32 -> bf16 convert: X then Wq|Wk|Wv|Wo ------------
// Grid-stride (G11): 2048 blocks, ~5 float4 units per thread.
__global__ __launch_bounds__(256) void cvtAll(const float* __restrict__ X,
                                              const float* __restrict__ Wq,
                                              const float* __restrict__ Wk,
                                              const float* __restrict__ Wv,
                                              const float* __restrict__ Wo,
                                              unsigned short* __restrict__ dstW,
                                              unsigned short* __restrict__ dstX) {
  const int NX = MROWS * EMBED, NW = EMBED * EMBED;
  const int total = (NX + 4 * NW) / 4;
  for (int u = blockIdx.x * 256 + threadIdx.x; u < total; u += gridDim.x * 256) {
    const int i = u * 4;
    const float* src;
    unsigned short* dst;
    if (i < NX) {
      src = X + i; dst = dstX + i;
    } else {
      int j = i - NX;
      int wsel = j / NW, r = j - wsel * NW;
      src = ((wsel == 0) ? Wq : (wsel == 1) ? Wk : (wsel == 2) ? Wv : Wo) + r;
      dst = dstW + j;
    }
    float4 v = *reinterpret_cast<const float4*>(src);
    uint2 o;
    o.x = pk2(v.x, v.y); o.y = pk2(v.z, v.w);
    *reinterpret_cast<uint2*>(dst) = o;
  }
}

// ---------------- GEMM: C[m,n] = sum_k A[m,k] * B[n,k]  (B stored [N][K]) ----
// R6-proven body. 1D grid, XCD-chunked bijective swizzle + n-fastest decompose.
// MODE 0: NB=9; scatters Q/K bf16 (Q scaled QSCALE); V transposed VT[bh][d][t].
// MODE 1: NB=3; fp32 out + bias.
template <int MODE>
__global__ __launch_bounds__(256) void gemm_bt(
    const unsigned short* __restrict__ Ab,
    const unsigned short* __restrict__ Bw,
    unsigned short* __restrict__ Qb,
    unsigned short* __restrict__ Kb,
    unsigned short* __restrict__ VT,
    float* __restrict__ Co,
    const float* __restrict__ bias) {
  constexpr int NB = (MODE == 0) ? 9 : 3;          // n-blocks per m-panel
  constexpr int NWG = (MROWS / 128) * NB;          // 1728 / 576, both %8==0
  __shared__ __align__(16) short SH[32768];   // 64KB: 2 bufs x (A 16KB + B 16KB)
  const int tid = threadIdx.x;
  const int lane = tid & 63;
  const int w = tid >> 6;
  const int wm = w >> 1, wn = w & 1;
  // XCD-chunked bijective swizzle (m204): XCD x gets work [x*NWG/8,(x+1)*NWG/8)
  const int work = ((int)blockIdx.x % 8) * (NWG / 8) + (int)blockIdx.x / 8;
  const int m0 = (work / NB) * 128, n0 = (work % NB) * 128;
  const int l15 = lane & 15, lg = lane >> 4;
  char* shc = (char*)SH;

  auto stage = [&](int kt, int buf) {
    short* At = SH + buf * 16384;
    short* Bt = At + 8192;
    const int k0 = kt * 64;
#pragma unroll
    for (int j = 0; j < 4; ++j) {
      const int u = j * 256 + tid;
      const int row = u >> 3, un = u & 7;
      const int sw = (un ^ (row & 7)) * 8;
      const int ub = (j * 256 + (tid & ~63)) * 8;
      GLD16(Ab + (size_t)(m0 + row) * EMBED + k0 + sw, At + ub);
      GLD16(Bw + (size_t)(n0 + row) * EMBED + k0 + sw, Bt + ub);
    }
  };

  f32x4 acc[4][4];
#pragma unroll
  for (int i = 0; i < 4; ++i)
#pragma unroll
    for (int j = 0; j < 4; ++j) acc[i][j] = f32x4{0.f, 0.f, 0.f, 0.f};

  stage(0, 0);
  int cur = 0;
#pragma unroll 1
  for (int kt = 0; kt < 6; ++kt) {
    __syncthreads();                        // drains stage(kt) [vmcnt(0) auto]
    if (kt < 5) stage(kt + 1, cur ^ 1);     // next-tile loads fly under MFMA
    const char* Ac = shc + cur * 32768;
    const char* Bc = Ac + 16384;
#pragma unroll
    for (int kc = 0; kc < 2; ++kc) {
      bf16x8 af[4], bfr[4];
#pragma unroll
      for (int mt = 0; mt < 4; ++mt) {
        const int row = wm * 64 + mt * 16 + l15;
        af[mt] = *(const bf16x8*)(Ac + row * 128 + (((kc * 4 + lg) ^ (row & 7)) * 16));
      }
#pragma unroll
      for (int nt = 0; nt < 4; ++nt) {
        const int row = wn * 64 + nt * 16 + l15;
        bfr[nt] = *(const bf16x8*)(Bc + row * 128 + (((kc * 4 + lg) ^ (row & 7)) * 16));
      }
#pragma unroll
      for (int mt = 0; mt < 4; ++mt)
#pragma unroll
        for (int nt = 0; nt < 4; ++nt)
          acc[mt][nt] = __builtin_amdgcn_mfma_f32_16x16x32_bf16(
              af[mt], bfr[nt], acc[mt][nt], 0, 0, 0);
    }
    cur ^= 1;
  }

  if (MODE == 0 && n0 >= 768) {
    // ---- V blocks: transpose via LDS (reuse buf0, 32KB), write VT coalesced --
    const int b = m0 / SEQ, t0 = m0 - b * SEQ;
    __syncthreads();
#pragma unroll
    for (int mt = 0; mt < 4; ++mt)
#pragma unroll
      for (int nt = 0; nt < 4; ++nt)
#pragma unroll
        for (int r = 0; r < 4; ++r) {
          const int tl = wm * 64 + mt * 16 + lg * 4 + r;
          const int nl = wn * 64 + nt * 16 + l15;
          *(unsigned short*)(shc + nl * 256 + (((tl >> 3) ^ (nl & 7)) * 16) +
                             (tl & 7) * 2) = nbf(acc[mt][nt][r]);
        }
    __syncthreads();
#pragma unroll
    for (int j = 0; j < 8; ++j) {
      const int u = j * 256 + tid;
      const int row = u >> 4, un = u & 15;
      int4 vv = *(const int4*)(shc + row * 256 + ((un ^ (row & 7)) * 16));
      const int cg = (n0 - 768) + row;
      const int h = cg >> 6, d = cg & 63;
      *(int4*)(VT + ((size_t)(b * NHEAD + h) * HSZ + d) * SEQ + t0 + un * 8) = vv;
    }
    return;
  }

  // block-uniform scatter bases (128-wide blocks straddle neither 384 nor 768)
  const int whichU = (MODE == 0) ? (n0 / EMBED) : 0;        // 0=Q, 1=K
  const int bU = m0 / SEQ;                                   // batch index
  const int tU = m0 - bU * SEQ;                              // seq base
#pragma unroll
  for (int mt = 0; mt < 4; ++mt) {
#pragma unroll
    for (int nt = 0; nt < 4; ++nt) {
#pragma unroll
      for (int r = 0; r < 4; ++r) {
        const int ml = wm * 64 + mt * 16 + lg * 4 + r;       // m offset in block
        const int n = n0 + wn * 64 + nt * 16 + l15;
        const float v = acc[mt][nt][r];
        if (MODE == 0) {
          const int c = n - whichU * EMBED;
          const int h = c >> 6, d = c & 63;
          const size_t off =
              ((size_t)((bU * NHEAD + h) * SEQ + tU + ml)) * HSZ + d;
          unsigned short* dstp = (whichU == 0) ? Qb : Kb;
          dstp[off] = nbf(whichU == 0 ? v * QSCALE : v);  // exp2-domain Q scale
        } else {
          Co[(size_t)(m0 + ml) * EMBED + n] = v + bias[n];
        }
      }
    }
  }
}

// ---------------- flash attention, causal, TRIPLE q-tiles per block ----------
// grid (8, 96): bh = (by/4)*8+bx (same-bh blocks share an XCD's L2).
// Block trip handles q-tiles {Q0,Q1,Q2}[trip]; one staged K/V tile feeds up
// to 3 tile() calls. 768 blocks = exactly 3/CU (LDS 40KB).
// exp2-domain softmax (R17) + defer-rescale THR=8 (T13) — the only delta
// vs R17: wave-uniform skip of {alpha, lp*=, o*=} when max growth <= 8.
__global__ __launch_bounds__(256, 3) void attn(const unsigned short* __restrict__ Qb,
                                               const unsigned short* __restrict__ Kb,
                                               const unsigned short* __restrict__ VT,
                                               unsigned short* __restrict__ AO) {
  __shared__ __align__(16) short Kt[2][64 * 64];   // [kv][d] swizzled, dbuf
  __shared__ __align__(16) short Vt[2][64 * 64];   // [d][kv] swizzled, dbuf
  __shared__ __align__(16) short Pl[4][16 * 64];   // per-wave P[q][kv] swizzled
  const int tid = threadIdx.x, lane = tid & 63, w = tid >> 6;
  const int l15 = lane & 15, lg = lane >> 4;
  const int trip = blockIdx.y & 3;
  const int bh = (blockIdx.y >> 2) * 8 + blockIdx.x;
  // balanced triples of q-tiles (each Σ(qt+1) = 19 or 20):
  const int q0t = trip;                                            // 0 1 2 3
  const int q1t = (trip == 3) ? 4 : trip + 5;                      // 5 6 7 4
  const int q2t = (trip == 0) ? 11 : (trip == 1) ? 10 : (trip == 2) ? 8 : 9;
  const size_t base = (size_t)bh * SEQ * HSZ;      // Qb/Kb [bh][t][d]
  char* pw = (char*)(&Pl[w][0]);

  bf16x8 qf0[2], qf1[2], qf2[2];
#pragma unroll
  for (int kc = 0; kc < 2; ++kc) {
    qf0[kc] = *(const bf16x8*)(Qb + base + (size_t)(q0t * 64 + w * 16 + l15) * HSZ +
                               kc * 32 + lg * 8);
    qf1[kc] = *(const bf16x8*)(Qb + base + (size_t)(q1t * 64 + w * 16 + l15) * HSZ +
                               kc * 32 + lg * 8);
    qf2[kc] = *(const bf16x8*)(Qb + base + (size_t)(q2t * 64 + w * 16 + l15) * HSZ +
                               kc * 32 + lg * 8);
  }

  f32x4 o0[4], o1[4], o2[4];
  float m0s = -3.0e38f, l0s = 0.f, m1s = -3.0e38f, l1s = 0.f;
  float m2s = -3.0e38f, l2s = 0.f;
#pragma unroll
  for (int nt = 0; nt < 4; ++nt) {
    o0[nt] = f32x4{0.f, 0.f, 0.f, 0.f};
    o1[nt] = f32x4{0.f, 0.f, 0.f, 0.f};
    o2[nt] = f32x4{0.f, 0.f, 0.f, 0.f};
  }

  auto stage = [&](int kt, int buf) {
#pragma unroll
    for (int j = 0; j < 2; ++j) {
      const int u = j * 256 + tid;
      const int row = u >> 3, un = u & 7;
      const int sw = (un ^ (row & 7)) * 8;
      const int ub = (j * 256 + (tid & ~63)) * 8;
      GLD16(Kb + base + (size_t)(kt * 64 + row) * HSZ + sw, &Kt[buf][ub]);
      GLD16(VT + base + (size_t)row * SEQ + kt * 64 + sw, &Vt[buf][ub]);
    }
  };

  // tile: S^T = mfma(K,Q); lane owns q=l15; exp2 softmax + defer-rescale
  auto tile = [&](const bf16x8* qf, const bf16x8 kf[2][4], const char* Vc,
                  f32x4* o, float& m, float& l, bool diag) {
    f32x4 s[4];
#pragma unroll
    for (int nt = 0; nt < 4; ++nt) s[nt] = f32x4{0.f, 0.f, 0.f, 0.f};
    __builtin_amdgcn_s_setprio(1);
#pragma unroll
    for (int kc = 0; kc < 2; ++kc)
#pragma unroll
      for (int nt = 0; nt < 4; ++nt)
        s[nt] = __builtin_amdgcn_mfma_f32_16x16x32_bf16(kf[kc][nt], qf[kc], s[nt],
                                                        0, 0, 0);
    __builtin_amdgcn_s_setprio(0);
    if (diag) {
#pragma unroll
      for (int nt = 0; nt < 4; ++nt)
#pragma unroll
        for (int r = 0; r < 4; ++r)
          if (nt * 16 + lg * 4 + r > w * 16 + l15) s[nt][r] = -3.0e38f;
    }
    float mx = s[0][0];
#pragma unroll
    for (int nt = 0; nt < 4; ++nt)
#pragma unroll
      for (int r = 0; r < 4; ++r) mx = fmaxf(mx, s[nt][r]);
    mx = fmaxf(mx, __shfl_xor(mx, 16, 64));
    mx = fmaxf(mx, __shfl_xor(mx, 32, 64));
    // defer-rescale (T13, THR=8 in log2 domain): P bounded by 2^8, fine in f32
    if (!__all(mx <= m + 8.f)) {
      const float mn = fmaxf(m, mx);
      const float alpha = __builtin_amdgcn_exp2f(m - mn);
      m = mn;
      l *= alpha;
#pragma unroll
      for (int nt = 0; nt < 4; ++nt) o[nt] *= alpha;
    }
    float srow = 0.f;
#pragma unroll
    for (int nt = 0; nt < 4; ++nt)
#pragma unroll
      for (int r = 0; r < 4; ++r) {
        const float e = __builtin_amdgcn_exp2f(s[nt][r] - m);
        s[nt][r] = e;
        srow += e;
      }
    srow += __shfl_xor(srow, 16, 64);
    srow += __shfl_xor(srow, 32, 64);
    l = l + srow;
#pragma unroll
    for (int nt = 0; nt < 4; ++nt) {
      const int kv = nt * 16 + lg * 4;
      int2 pv;
      pv.x = (int)pk2(s[nt][0], s[nt][1]);
      pv.y = (int)pk2(s[nt][2], s[nt][3]);
      *(int2*)(pw + l15 * 128 + (((kv >> 3) ^ (l15 & 7)) * 16) + (kv & 7) * 2) = pv;
    }
    asm volatile("" ::: "memory");
    bf16x8 pf[2];
#pragma unroll
    for (int kc = 0; kc < 2; ++kc)
      pf[kc] = *(const bf16x8*)(pw + l15 * 128 + (((kc * 4 + lg) ^ (l15 & 7)) * 16));
    __builtin_amdgcn_s_setprio(1);
#pragma unroll
    for (int kc = 0; kc < 2; ++kc)
#pragma unroll
      for (int nt = 0; nt < 4; ++nt) {
        const int row = nt * 16 + l15;
        bf16x8 vf = *(const bf16x8*)(Vc + row * 128 +
                                     (((kc * 4 + lg) ^ (row & 7)) * 16));
        o[nt] = __builtin_amdgcn_mfma_f32_16x16x32_bf16(vf, pf[kc], o[nt], 0, 0, 0);
      }
    __builtin_amdgcn_s_setprio(0);
  };

  stage(0, 0);
  int cur = 0;
#pragma unroll 1
  for (int kt = 0; kt <= q2t; ++kt) {
    __syncthreads();                        // buf[cur] staged; buf[cur^1] free
    if (kt < q2t) stage(kt + 1, cur ^ 1);   // loads fly under compute
    const char* Kc = (const char*)Kt[cur];
    const char* Vc = (const char*)Vt[cur];
    bf16x8 kf[2][4];
#pragma unroll
    for (int kc = 0; kc < 2; ++kc)
#pragma unroll
      for (int nt = 0; nt < 4; ++nt) {
        const int row = nt * 16 + l15;
        kf[kc][nt] = *(const bf16x8*)(Kc + row * 128 +
                                      (((kc * 4 + lg) ^ (row & 7)) * 16));
      }
    tile(qf2, kf, Vc, o2, m2s, l2s, kt == q2t);
    if (kt <= q1t) tile(qf1, kf, Vc, o1, m1s, l1s, kt == q1t);
    if (kt <= q0t) tile(qf0, kf, Vc, o0, m0s, l0s, kt == q0t);
    cur ^= 1;
  }

  // epilogue: lane holds O[q=l15][d=nt*16+lg*4+r]; ushort4 stores x3
  const int bq = bh / NHEAD, h = bh - bq * NHEAD;
  const float inv0 = 1.f / l0s, inv1 = 1.f / l1s, inv2 = 1.f / l2s;
#pragma unroll
  for (int nt = 0; nt < 4; ++nt) {
    ushort4 s0, s1, s2;
    s0.x = nbf(o0[nt][0] * inv0); s0.y = nbf(o0[nt][1] * inv0);
    s0.z = nbf(o0[nt][2] * inv0); s0.w = nbf(o0[nt][3] * inv0);
    s1.x = nbf(o1[nt][0] * inv1); s1.y = nbf(o1[nt][1] * inv1);
    s1.z = nbf(o1[nt][2] * inv1); s1.w = nbf(o1[nt][3] * inv1);
    s2.x = nbf(o2[nt][0] * inv2); s2.y = nbf(o2[nt][1] * inv2);
    s2.z = nbf(o2[nt][2] * inv2); s2.w = nbf(o2[nt][3] * inv2);
    const int col = h * HSZ + nt * 16 + lg * 4;
    *(ushort4*)(AO + ((size_t)(bq * SEQ + q0t * 64 + w * 16 + l15)) * EMBED + col) = s0;
    *(ushort4*)(AO + ((size_t)(bq * SEQ + q1t * 64 + w * 16 + l15)) * EMBED + col) = s1;
    *(ushort4*)(AO + ((size_t)(bq * SEQ + q2t * 64 + w * 16 + l15)) * EMBED + col) = s2;
  }
}

extern "C" void kernel_launch(void* const* d_in, const int* in_sizes, int n_in,
                              void* d_out, int out_size, void* d_ws, size_t ws_size,
                              hipStream_t stream) {
  const float* X  = (const float*)d_in[0];
  const float* Wq = (const float*)d_in[1];
  const float* Wk = (const float*)d_in[2];
  const float* Wv = (const float*)d_in[3];
  const float* Wo = (const float*)d_in[4];
  const float* bo = (const float*)d_in[5];
  float* out = (float*)d_out;

  const size_t NW = (size_t)EMBED * EMBED;   // 147456
  const size_t NX = (size_t)MROWS * EMBED;   // 9437184
  unsigned short* ws    = (unsigned short*)d_ws;
  unsigned short* Wqkvb = ws;                // 3*NW
  unsigned short* Wob   = Wqkvb + 3 * NW;    // NW (contiguous after Wqkvb)
  unsigned short* XbAO  = Wob + NW;          // NX: Xb (pre-attn) then AO
  unsigned short* Qb    = XbAO + NX;         // NX  [B,H,T,D]
  unsigned short* Kb    = Qb + NX;           // NX  [B,H,T,D]
  unsigned short* VTb   = Kb + NX;           // NX  [B,H,D,T] (transposed V)
  // total: 4*NW + 4*NX ushorts = 76.7 MB of d_ws

  cvtAll<<<2048, 256, 0, stream>>>(X, Wq, Wk, Wv, Wo, Wqkvb, XbAO);

  gemm_bt<0><<<(MROWS / 128) * 9, 256, 0, stream>>>(
      XbAO, Wqkvb, Qb, Kb, VTb, nullptr, nullptr);

  attn<<<dim3(8, 96), 256, 0, stream>>>(Qb, Kb, VTb, XbAO);

  gemm_bt<1><<<(MROWS / 128) * 3, 256, 0, stream>>>(
      XbAO, Wob, nullptr, nullptr, nullptr, out, bo);
}